// Round 11
// baseline (511.768 us; speedup 1.0000x reference)
//
#include <hip/hip_runtime.h>

#define K_OFF   8
#define R_PAIRS 62500
#define NPAIRS  500000
#define N_IN    500000
#define N_OUT   125000
#define CIN     64
#define COUT    128
#define BN_EPS  1e-4f
#define SCAN_ELEMS 4096
#define NBINS_KC (N_OUT * K_OFF)     // 1,000,000
#define NSB_KC  245                  // ceil(1e6 / 4096)
#define BM      32
#define OLD_TILES 8

typedef __bf16 bf16;
typedef __bf16 bf16x8 __attribute__((ext_vector_type(8)));
typedef float  f32x4  __attribute__((ext_vector_type(4)));
typedef unsigned int u32;

// bf16-z byte-offset swizzle: row-stride 1024B, inject row low bits into 16B-slot bits.
__device__ __forceinline__ int zb(int row, int col_bf16) {
    int byte = (row << 10) + (col_bf16 << 1);
    return byte ^ ((row & 7) << 4);
}

// ==================== BN statistics ====================
template<int C>
__global__ void bn_stats_kernel(const float* __restrict__ x, int n_rows,
                                float* __restrict__ sums /* [2C] */) {
    constexpr int CG = C / 4;
    int tid = blockIdx.x * blockDim.x + threadIdx.x;
    int nth = gridDim.x * blockDim.x;
    const float4* x4 = (const float4*)x;
    long n4 = (long)n_rows * CG;
    int cg = tid % CG;
    float s[4] = {0,0,0,0}, q[4] = {0,0,0,0};
    for (long i = tid; i < n4; i += nth) {
        float4 v = x4[i];
        float f[4] = {v.x, v.y, v.z, v.w};
        #pragma unroll
        for (int j = 0; j < 4; j++) { s[j] += f[j]; q[j] += f[j] * f[j]; }
    }
    __shared__ float acc[2 * C];
    for (int i = threadIdx.x; i < 2 * C; i += blockDim.x) acc[i] = 0.f;
    __syncthreads();
    #pragma unroll
    for (int j = 0; j < 4; j++) {
        atomicAdd(&acc[cg * 4 + j], s[j]);
        atomicAdd(&acc[C + cg * 4 + j], q[j]);
    }
    __syncthreads();
    for (int i = threadIdx.x; i < 2 * C; i += blockDim.x) atomicAdd(&sums[i], acc[i]);
}

template<int C>
__global__ void bn_finalize_kernel(const float* __restrict__ sums,
                                   const float* __restrict__ gamma,
                                   const float* __restrict__ beta,
                                   float inv_n, float* __restrict__ ss) {
    int c = threadIdx.x;
    if (c < C) {
        float m  = sums[c] * inv_n;
        float v  = sums[C + c] * inv_n - m * m;
        float sc = gamma[c] * rsqrtf(v + BN_EPS);
        ss[c]     = sc;
        ss[C + c] = beta[c] - m * sc;
    }
}

// BN2 finalize from 64 striped partial-sum copies
__global__ void bn_finalize2_kernel(const float* __restrict__ S /*[64][256]*/,
                                    const float* __restrict__ gamma,
                                    const float* __restrict__ beta,
                                    float* __restrict__ ss) {
    int c = threadIdx.x;   // 128
    float s = 0.f, q = 0.f;
    for (int st = 0; st < 64; st++) { s += S[st * 256 + c]; q += S[st * 256 + 128 + c]; }
    float m = s / (float)N_OUT;
    float v = q / (float)N_OUT - m * m;
    float sc = gamma[c] * rsqrtf(v + BN_EPS);
    ss[c] = sc; ss[128 + c] = beta[c] - m * sc;
}

// ==================== BN apply + ReLU -> bf16 (fp32 in) ====================
template<int C>
__global__ void bn_apply_f32_kernel(const float* __restrict__ x, const float* __restrict__ ss,
                                    bf16* __restrict__ xo, long items /* rows*C/8 */) {
    constexpr int CG = C / 8;
    long i = (long)blockIdx.x * blockDim.x + threadIdx.x;
    long stride = (long)gridDim.x * blockDim.x;   // multiple of CG
    int cg = (int)(i % CG);
    float sc[8], sh[8];
    #pragma unroll
    for (int j = 0; j < 8; j++) { sc[j] = ss[cg*8+j]; sh[j] = ss[C + cg*8+j]; }
    for (; i < items; i += stride) {
        const float4* p = (const float4*)(x + i * 8);
        float4 a = p[0], b = p[1];
        float f[8] = {a.x,a.y,a.z,a.w,b.x,b.y,b.z,b.w};
        bf16x8 h;
        #pragma unroll
        for (int j = 0; j < 8; j++) h[j] = (bf16)fmaxf(f[j]*sc[j] + sh[j], 0.f);
        *(bf16x8*)(xo + i * 8) = h;
    }
}

// ==================== weight prepack (fragment order) ====================
__global__ void pack12_kernel(const float* __restrict__ W1, const float* __restrict__ W2,
                              bf16* __restrict__ Wf) {
    int idx = blockIdx.x * 256 + threadIdx.x;      // 131072
    int j = idx & 7;
    int lane = (idx >> 3) & 63;
    int fi = idx >> 9;            // 0..255
    int ks = fi >> 4, nfrag = fi & 15;
    int k512 = ks * 32 + (lane >> 4) * 8 + j;
    int koff = k512 >> 6, kc = k512 & 63;
    int c = nfrag * 16 + (lane & 15);
    const float* W = (c < 128) ? W1 : W2;
    Wf[idx] = (bf16)W[((long)koff * CIN + kc) * COUT + (c & 127)];
}

__global__ void packS_kernel(const float* __restrict__ Ws, bf16* __restrict__ Wf) {
    int idx = blockIdx.x * 256 + threadIdx.x;      // 131072
    int j = idx & 7;
    int lane = (idx >> 3) & 63;
    int fi = idx >> 9;            // 0..255
    int ksg = fi >> 3, nfrag = fi & 7;
    int k1024 = ksg * 32 + (lane >> 4) * 8 + j;
    int koff = k1024 >> 7, kc = k1024 & 127;
    int c = nfrag * 16 + (lane & 15);
    Wf[idx] = (bf16)Ws[((long)koff * COUT + kc) * COUT + c];
}

// ==================== hist over (out,k) bins ====================
__global__ void histOK_kernel(const int* __restrict__ oidx, u32* __restrict__ counts) {
    int p = blockIdx.x * blockDim.x + threadIdx.x;
    int stride = gridDim.x * blockDim.x;
    for (; p < NPAIRS; p += stride) {
        int bin = oidx[p] * K_OFF + p / R_PAIRS;
        atomicAdd(&counts[bin], 1u);
    }
}

// ==================== 3-level scan ====================
__global__ void scan1_kernel(const u32* __restrict__ counts, u32* __restrict__ bsum, int n) {
    __shared__ u32 sd[256];
    int tid = threadIdx.x;
    int base = blockIdx.x * SCAN_ELEMS + tid * 16;
    u32 s = 0;
    #pragma unroll
    for (int j = 0; j < 16; j++) { int i = base + j; if (i < n) s += counts[i]; }
    sd[tid] = s; __syncthreads();
    for (int st = 128; st > 0; st >>= 1) { if (tid < st) sd[tid] += sd[tid + st]; __syncthreads(); }
    if (tid == 0) bsum[blockIdx.x] = sd[0];
}

__global__ void scan2_kernel(u32* __restrict__ bsum, u32* __restrict__ starts, int nb, int n) {
    __shared__ u32 sd[256];
    int tid = threadIdx.x;
    u32 v = (tid < nb) ? bsum[tid] : 0;
    sd[tid] = v; __syncthreads();
    for (int st = 1; st < 256; st <<= 1) {
        u32 t = (tid >= st) ? sd[tid - st] : 0;
        __syncthreads();
        sd[tid] += t;
        __syncthreads();
    }
    if (tid < nb) bsum[tid] = sd[tid] - v;     // exclusive
    if (tid == 255) starts[n] = sd[255];       // total
}

__global__ void scan3_kernel(const u32* __restrict__ counts, const u32* __restrict__ bsum,
                             u32* __restrict__ starts, int n) {
    __shared__ u32 sd[256];
    int tid = threadIdx.x;
    int base = blockIdx.x * SCAN_ELEMS + tid * 16;
    u32 v[16]; u32 s = 0;
    #pragma unroll
    for (int j = 0; j < 16; j++) { int i = base + j; v[j] = (i < n) ? counts[i] : 0; s += v[j]; }
    sd[tid] = s; __syncthreads();
    for (int st = 1; st < 256; st <<= 1) {
        u32 t = (tid >= st) ? sd[tid - st] : 0;
        __syncthreads();
        sd[tid] += t;
        __syncthreads();
    }
    u32 run = bsum[blockIdx.x] + sd[tid] - s;
    #pragma unroll
    for (int j = 0; j < 16; j++) { int i = base + j; if (i < n) starts[i] = run; run += v[j]; }
}

// ==================== build (out,k)-sorted gather list (cursor = counts, atomicSub) ==
__global__ void buildF_kernel(const int* __restrict__ iidx, const int* __restrict__ oidx,
                              const u32* __restrict__ kstart, u32* __restrict__ counts,
                              u32* __restrict__ listF) {
    int p = blockIdx.x * 256 + threadIdx.x;
    if (p >= NPAIRS) return;
    int bin = oidx[p] * K_OFF + p / R_PAIRS;
    u32 c = atomicSub(&counts[bin], 1u);
    listF[kstart[bin] + c - 1u] = (u32)iidx[p];
}

// ==================== fused conv1+conv2: BM=32, bf16 z, 2 m-tiles/wave ==============
// Thread (myr=tid>>4, sl=tid&15) owns rows {myr, myr+16}, k=sl>>1, ch 32-slice (sl&1).
// z [32][512] bf16 (32 KB), swizzled zb. GEMM: wave w -> cat cols w*64..+64, 2 m-tiles.
__global__ __launch_bounds__(256) void fused12_kernel(
    const bf16* __restrict__ x1, const bf16* __restrict__ Wf,
    const u32* __restrict__ kstart, const u32* __restrict__ listF,
    bf16* __restrict__ y1, bf16* __restrict__ y2b, float* __restrict__ sums2s)
{
    __shared__ bf16 z[BM * 512];      // 32 KB
    int tid = threadIdx.x, lane = tid & 63, wave = tid >> 6;
    int o0 = blockIdx.x * BM;
    int nrow = min(BM, N_OUT - o0);

    int myr = tid >> 4, sl = tid & 15;
    int kown = sl >> 1, ch0 = (sl & 1) * 32;

    f32x4 a0[8], a1[8];
    #pragma unroll
    for (int g = 0; g < 8; g++) { a0[g] = (f32x4)(0.f); a1[g] = (f32x4)(0.f); }

    auto gatherRow = [&](f32x4 (&a)[8], int row) {
        if (o0 + row >= N_OUT) return;
        long bin = (long)(o0 + row) * K_OFF + kown;
        u32 s = kstart[bin], e = kstart[bin + 1];
        for (u32 p = s; p < e; p++) {
            int in = (int)listF[p];
            const int4* src = (const int4*)(x1 + (size_t)in * 64 + ch0);
            #pragma unroll
            for (int q = 0; q < 4; q++) {
                int4 vi = src[q];
                bf16x8 hv = *(bf16x8*)&vi;
                #pragma unroll
                for (int j = 0; j < 8; j++)
                    a[q * 2 + (j >> 2)][j & 3] += (float)hv[j];
            }
        }
    };
    gatherRow(a0, myr);
    gatherRow(a1, myr + 16);

    auto zwrite = [&](f32x4 (&a)[8], int row) {
        int colb = sl * 32;    // == kown*64 + ch0
        #pragma unroll
        for (int u = 0; u < 4; u++) {
            bf16x8 h;
            #pragma unroll
            for (int j = 0; j < 8; j++) h[j] = (bf16)a[u * 2 + (j >> 2)][j & 3];
            *(bf16x8*)((char*)z + zb(row, colb + u * 8)) = h;
        }
    };
    zwrite(a0, myr);
    zwrite(a1, myr + 16);
    __syncthreads();

    // ---- GEMM: [32 x 512] x [512 x 256], 2 m-tiles per wave ----
    int l15 = lane & 15, kr0 = (lane >> 4) * 8;
    f32x4 acc[2][4];
    #pragma unroll
    for (int m = 0; m < 2; m++)
        #pragma unroll
        for (int nf = 0; nf < 4; nf++) acc[m][nf] = (f32x4)(0.f);

    for (int ks = 0; ks < 16; ks++) {
        int colb = ks * 32 + kr0;
        bf16x8 af0 = *(bf16x8*)((char*)z + zb(l15, colb));
        bf16x8 af1 = *(bf16x8*)((char*)z + zb(l15 + 16, colb));
        #pragma unroll
        for (int nf = 0; nf < 4; nf++) {
            bf16x8 bf = *(const bf16x8*)(Wf + ((size_t)(ks * 16 + wave * 4 + nf) * 64 + lane) * 8);
            acc[0][nf] = __builtin_amdgcn_mfma_f32_16x16x32_bf16(af0, bf, acc[0][nf], 0, 0, 0);
            acc[1][nf] = __builtin_amdgcn_mfma_f32_16x16x32_bf16(af1, bf, acc[1][nf], 0, 0, 0);
        }
    }
    __syncthreads();   // all z reads done -> reuse as stage

    // stage bf16 [32 rows][256 cat cols] (16 KB, inside z)
    bf16* st = z;
    int rb = (lane >> 4) * 4;
    #pragma unroll
    for (int m = 0; m < 2; m++)
        #pragma unroll
        for (int nf = 0; nf < 4; nf++)
            #pragma unroll
            for (int j = 0; j < 4; j++)
                st[(m * 16 + rb + j) * 256 + wave * 64 + nf * 16 + l15] = (bf16)acc[m][nf][j];
    __syncthreads();

    // BN2 stats over y1 cols (0..127), striped atomics
    if (tid < 128) {
        float s = 0.f, q = 0.f;
        for (int r = 0; r < nrow; r++) { float v = (float)st[r * 256 + tid]; s += v; q += v * v; }
        int sb = (blockIdx.x & 63) * 256;
        atomicAdd(&sums2s[sb + tid], s);
        atomicAdd(&sums2s[sb + 128 + tid], q);
    }
    // output: 512 (row, 32B-segment) slots over 2 iterations
    #pragma unroll
    for (int it = 0; it < 2; it++) {
        int slot = tid + it * 256;
        int row = slot >> 4, seg = slot & 15;
        if (row < nrow) {
            const int4* src = (const int4*)(st + row * 256 + seg * 16);
            int4 v0 = src[0], v1 = src[1];
            bf16* dst = (seg < 8) ? (y1  + (size_t)(o0 + row) * 128 + seg * 16)
                                  : (y2b + (size_t)(o0 + row) * 128 + (seg - 8) * 16);
            ((int4*)dst)[0] = v0; ((int4*)dst)[1] = v1;
        }
    }
}

// ==================== fused submanifold conv: BM=32, bf16 z, per-half gather ========
// Thread (myr, sl): rows {myr, myr+16}, ch slice (sl&3)*32, k = h*4 + (sl>>2) per half.
__global__ __launch_bounds__(256) void fusedS_kernel(
    const bf16* __restrict__ y1, const bf16* __restrict__ Wf, const float* __restrict__ ss2,
    const u32* __restrict__ kstart, const u32* __restrict__ listF,
    const bf16* __restrict__ y2b, float* __restrict__ out)
{
    __shared__ bf16 z[BM * 512];      // 32 KB
    __shared__ float s_sc[128], s_sh[128];
    int tid = threadIdx.x, lane = tid & 63, wave = tid >> 6;
    if (tid < 128) { s_sc[tid] = ss2[tid]; s_sh[tid] = ss2[128 + tid]; }
    int o0 = blockIdx.x * BM;
    int nrow = min(BM, N_OUT - o0);

    int myr = tid >> 4, sl = tid & 15;
    int kq = sl >> 2, ch0 = (sl & 3) * 32;
    int l15 = lane & 15, kr0 = (lane >> 4) * 8;

    __syncthreads();   // s_sc/s_sh ready

    f32x4 acc[2][2];
    #pragma unroll
    for (int m = 0; m < 2; m++)
        #pragma unroll
        for (int nf = 0; nf < 2; nf++) acc[m][nf] = (f32x4)(0.f);

    for (int h = 0; h < 2; h++) {
        f32x4 a0[8], a1[8];
        #pragma unroll
        for (int g = 0; g < 8; g++) { a0[g] = (f32x4)(0.f); a1[g] = (f32x4)(0.f); }

        auto gatherRow = [&](f32x4 (&a)[8], int row) {
            if (o0 + row >= N_OUT) return;
            long bin = (long)(o0 + row) * K_OFF + h * 4 + kq;
            u32 s = kstart[bin], e = kstart[bin + 1];
            for (u32 p = s; p < e; p++) {
                int in = (int)listF[p];
                const int4* src = (const int4*)(y1 + (size_t)in * 128 + ch0);
                #pragma unroll
                for (int q = 0; q < 4; q++) {
                    int4 vi = src[q];
                    bf16x8 hv = *(bf16x8*)&vi;
                    #pragma unroll
                    for (int j = 0; j < 8; j++) {
                        int c = ch0 + q * 8 + j;
                        a[q * 2 + (j >> 2)][j & 3] +=
                            fmaxf((float)hv[j] * s_sc[c] + s_sh[c], 0.f);
                    }
                }
            }
        };
        gatherRow(a0, myr);
        gatherRow(a1, myr + 16);

        if (h) __syncthreads();   // GEMM h=0 z reads done

        auto zwrite = [&](f32x4 (&a)[8], int row) {
            int colb = sl * 32;    // == kq*128 + ch0
            #pragma unroll
            for (int u = 0; u < 4; u++) {
                bf16x8 hv;
                #pragma unroll
                for (int j = 0; j < 8; j++) hv[j] = (bf16)a[u * 2 + (j >> 2)][j & 3];
                *(bf16x8*)((char*)z + zb(row, colb + u * 8)) = hv;
            }
        };
        zwrite(a0, myr);
        zwrite(a1, myr + 16);
        __syncthreads();

        for (int ks = 0; ks < 16; ks++) {
            int colb = ks * 32 + kr0;
            bf16x8 af0 = *(bf16x8*)((char*)z + zb(l15, colb));
            bf16x8 af1 = *(bf16x8*)((char*)z + zb(l15 + 16, colb));
            #pragma unroll
            for (int nf = 0; nf < 2; nf++) {
                int fi = (h * 16 + ks) * 8 + wave * 2 + nf;
                bf16x8 bf = *(const bf16x8*)(Wf + ((size_t)fi * 64 + lane) * 8);
                acc[0][nf] = __builtin_amdgcn_mfma_f32_16x16x32_bf16(af0, bf, acc[0][nf], 0, 0, 0);
                acc[1][nf] = __builtin_amdgcn_mfma_f32_16x16x32_bf16(af1, bf, acc[1][nf], 0, 0, 0);
            }
        }
    }
    __syncthreads();

    // stage fp32 [32][128] (16 KB, inside z)
    float* zf = (float*)z;
    int rb = (lane >> 4) * 4;
    #pragma unroll
    for (int m = 0; m < 2; m++)
        #pragma unroll
        for (int nf = 0; nf < 2; nf++)
            #pragma unroll
            for (int j = 0; j < 4; j++)
                zf[(m * 16 + rb + j) * 128 + wave * 32 + nf * 16 + l15] = acc[m][nf][j];
    __syncthreads();

    #pragma unroll
    for (int it = 0; it < 2; it++) {
        int slot = tid + it * 256;
        int row = slot >> 4, seg = slot & 15;   // 8 floats each
        if (row < nrow) {
            f32x4 s0 = *(f32x4*)&zf[row * 128 + seg * 8];
            f32x4 s1 = *(f32x4*)&zf[row * 128 + seg * 8 + 4];
            int4 yv = *(const int4*)(y2b + (size_t)(o0 + row) * 128 + seg * 8);
            bf16x8 hy = *(bf16x8*)&yv;
            float4 w0 = make_float4(s0[0] + (float)hy[0], s0[1] + (float)hy[1],
                                    s0[2] + (float)hy[2], s0[3] + (float)hy[3]);
            float4 w1 = make_float4(s1[0] + (float)hy[4], s1[1] + (float)hy[5],
                                    s1[2] + (float)hy[6], s1[3] + (float)hy[7]);
            float* dst = out + (size_t)(o0 + row) * 128 + seg * 8;
            *(float4*)dst = w0;
            *(float4*)(dst + 4) = w1;
        }
    }
}

// ==================== fallback (round-1 atomic path) ====================
__global__ __launch_bounds__(256) void conv12_atomic_kernel(
    const float* __restrict__ x,
    const float* __restrict__ W1, const float* __restrict__ W2,
    const int* __restrict__ in_idx, const int* __restrict__ out_idx,
    const float* __restrict__ ss1,
    float* __restrict__ y1, float* __restrict__ y2)
{
    int k    = blockIdx.y;
    int tid  = threadIdx.x;
    int wave = tid >> 6, lane = tid & 63;

    __shared__ bf16 As[64 * 64];
    __shared__ int  s_out[64];
    __shared__ float s_sc[64], s_sh[64];
    char* asb = (char*)As;

    if (tid < 64) { s_sc[tid] = ss1[tid]; s_sh[tid] = ss1[64 + tid]; }

    const float* Wk = ((wave & 2) ? W2 : W1) + (long)k * CIN * COUT;
    int nbase = (wave & 1) * 64;
    int l15 = lane & 15;
    int kr0 = (lane >> 4) * 8;

    bf16x8 bfrag[2][4];
    #pragma unroll
    for (int ks = 0; ks < 2; ks++)
        #pragma unroll
        for (int nf = 0; nf < 4; nf++) {
            const float* p = Wk + (long)(ks * 32 + kr0) * COUT + nbase + nf * 16 + l15;
            bf16x8 b;
            #pragma unroll
            for (int j = 0; j < 8; j++) b[j] = (bf16)p[(long)j * COUT];
            bfrag[ks][nf] = b;
        }

    const int* in_k  = in_idx  + k * R_PAIRS;
    const int* out_k = out_idx + k * R_PAIRS;
    float* ybase = (wave & 2) ? y2 : y1;

    int grow = tid >> 2;
    int gcol = (tid & 3) * 16;

    __syncthreads();

    for (int t = 0; t < OLD_TILES; t++) {
        int pair0 = blockIdx.x * (OLD_TILES * 64) + t * 64;
        {
            int p = pair0 + grow;
            bool valid = p < R_PAIRS;
            long src = valid ? (long)in_k[p] : 0;
            const float4* xr = (const float4*)(x + src * CIN + gcol);
            #pragma unroll
            for (int g = 0; g < 2; g++) {
                float4 va = make_float4(0, 0, 0, 0), vb = va;
                if (valid) { va = xr[g * 2]; vb = xr[g * 2 + 1]; }
                float f[8] = {va.x, va.y, va.z, va.w, vb.x, vb.y, vb.z, vb.w};
                bf16x8 h;
                #pragma unroll
                for (int j = 0; j < 8; j++) {
                    int c = gcol + g * 8 + j;
                    h[j] = (bf16)fmaxf(f[j] * s_sc[c] + s_sh[c], 0.f);
                }
                int boff = ((grow * 128) + (gcol + g * 8) * 2) ^ ((grow & 7) << 4);
                *(bf16x8*)(asb + boff) = h;
            }
        }
        if (tid < 64) {
            int p = pair0 + tid;
            s_out[tid] = (p < R_PAIRS) ? out_k[p] : -1;
        }
        __syncthreads();

        f32x4 acc[4][4];
        #pragma unroll
        for (int m = 0; m < 4; m++)
            #pragma unroll
            for (int n = 0; n < 4; n++) acc[m][n] = (f32x4)(0.f);

        #pragma unroll
        for (int ks = 0; ks < 2; ks++) {
            bf16x8 af[4];
            #pragma unroll
            for (int m = 0; m < 4; m++) {
                int row = m * 16 + l15;
                int boff = (row * 128 + (ks * 32 + kr0) * 2) ^ ((row & 7) << 4);
                af[m] = *(bf16x8*)(asb + boff);
            }
            #pragma unroll
            for (int m = 0; m < 4; m++)
                #pragma unroll
                for (int nf = 0; nf < 4; nf++)
                    acc[m][nf] = __builtin_amdgcn_mfma_f32_16x16x32_bf16(
                        af[m], bfrag[ks][nf], acc[m][nf], 0, 0, 0);
        }

        int rbase = (lane >> 4) * 4;
        #pragma unroll
        for (int m = 0; m < 4; m++)
            #pragma unroll
            for (int j = 0; j < 4; j++) {
                int o = s_out[m * 16 + rbase + j];
                if (o >= 0)
                    #pragma unroll
                    for (int nf = 0; nf < 4; nf++)
                        atomicAdd(&ybase[(long)o * COUT + nbase + nf * 16 + l15],
                                  acc[m][nf][j]);
            }
        __syncthreads();
    }
}

__global__ __launch_bounds__(256) void convs_atomic_kernel(
    const float* __restrict__ y1,
    const float* __restrict__ Ws,
    const int* __restrict__ in_idx, const int* __restrict__ out_idx,
    const float* __restrict__ ss2,
    float* __restrict__ out)
{
    int k    = blockIdx.y;
    int tid  = threadIdx.x;
    int wave = tid >> 6, lane = tid & 63;

    __shared__ bf16 As[64 * 128];
    __shared__ int  s_out[64];
    __shared__ float s_sc[128], s_sh[128];
    char* asb = (char*)As;

    if (tid < 128) { s_sc[tid] = ss2[tid]; s_sh[tid] = ss2[128 + tid]; }

    const float* Wk = Ws + (long)k * COUT * COUT;
    int nbase = wave * 32;
    int l15 = lane & 15;
    int kr0 = (lane >> 4) * 8;

    bf16x8 bfrag[4][2];
    #pragma unroll
    for (int ks = 0; ks < 4; ks++)
        #pragma unroll
        for (int nf = 0; nf < 2; nf++) {
            const float* p = Wk + (long)(ks * 32 + kr0) * COUT + nbase + nf * 16 + l15;
            bf16x8 b;
            #pragma unroll
            for (int j = 0; j < 8; j++) b[j] = (bf16)p[(long)j * COUT];
            bfrag[ks][nf] = b;
        }

    const int* in_k  = in_idx  + k * R_PAIRS;
    const int* out_k = out_idx + k * R_PAIRS;

    int grow = tid >> 2;
    int gcol = (tid & 3) * 32;

    __syncthreads();

    for (int t = 0; t < OLD_TILES; t++) {
        int pair0 = blockIdx.x * (OLD_TILES * 64) + t * 64;
        {
            int p = pair0 + grow;
            bool valid = p < R_PAIRS;
            long src = valid ? (long)in_k[p] : 0;
            const float4* yr = (const float4*)(y1 + src * COUT + gcol);
            #pragma unroll
            for (int g = 0; g < 4; g++) {
                float4 va = make_float4(0, 0, 0, 0), vb = va;
                if (valid) { va = yr[g * 2]; vb = yr[g * 2 + 1]; }
                float f[8] = {va.x, va.y, va.z, va.w, vb.x, vb.y, vb.z, vb.w};
                bf16x8 h;
                #pragma unroll
                for (int j = 0; j < 8; j++) {
                    int c = gcol + g * 8 + j;
                    h[j] = (bf16)fmaxf(f[j] * s_sc[c] + s_sh[c], 0.f);
                }
                int boff = (grow * 256 + (gcol + g * 8) * 2) ^ ((grow & 7) << 4);
                *(bf16x8*)(asb + boff) = h;
            }
        }
        if (tid < 64) {
            int p = pair0 + tid;
            s_out[tid] = (p < R_PAIRS) ? out_k[p] : -1;
        }
        __syncthreads();

        f32x4 acc[4][2];
        #pragma unroll
        for (int m = 0; m < 4; m++)
            #pragma unroll
            for (int n = 0; n < 2; n++) acc[m][n] = (f32x4)(0.f);

        #pragma unroll
        for (int ks = 0; ks < 4; ks++) {
            bf16x8 af[4];
            #pragma unroll
            for (int m = 0; m < 4; m++) {
                int row = m * 16 + l15;
                int boff = (row * 256 + (ks * 32 + kr0) * 2) ^ ((row & 7) << 4);
                af[m] = *(bf16x8*)(asb + boff);
            }
            #pragma unroll
            for (int m = 0; m < 4; m++)
                #pragma unroll
                for (int nf = 0; nf < 2; nf++)
                    acc[m][nf] = __builtin_amdgcn_mfma_f32_16x16x32_bf16(
                        af[m], bfrag[ks][nf], acc[m][nf], 0, 0, 0);
        }

        int rbase = (lane >> 4) * 4;
        #pragma unroll
        for (int m = 0; m < 4; m++)
            #pragma unroll
            for (int j = 0; j < 4; j++) {
                int o = s_out[m * 16 + rbase + j];
                if (o >= 0)
                    #pragma unroll
                    for (int nf = 0; nf < 2; nf++)
                        atomicAdd(&out[(long)o * COUT + nbase + nf * 16 + l15],
                                  acc[m][nf][j]);
            }
        __syncthreads();
    }
}

// ==================== host ====================
extern "C" void kernel_launch(void* const* d_in, const int* in_sizes, int n_in,
                              void* d_out, int out_size, void* d_ws, size_t ws_size,
                              hipStream_t stream) {
    const float* x       = (const float*)d_in[0];
    const float* gamma1  = (const float*)d_in[1];
    const float* beta1   = (const float*)d_in[2];
    const float* gamma2  = (const float*)d_in[3];
    const float* beta2   = (const float*)d_in[4];
    const float* W1      = (const float*)d_in[5];
    const float* Ws      = (const float*)d_in[6];
    const float* W2      = (const float*)d_in[7];
    const int*   in_idx1   = (const int*)d_in[8];
    const int*   out_idx1  = (const int*)d_in[9];
    const int*   in_idx_s  = (const int*)d_in[10];
    const int*   out_idx_s = (const int*)d_in[11];

    float* out = (float*)d_out;
    char*  ws  = (char*)d_ws;

    auto a256 = [](size_t v) { return (v + 255) & ~(size_t)255; };

    size_t off_y1      = 0;                                    // bf16 y1: 32 MB
    size_t off_x1      = a256(off_y1 + 32000000);              // bf16 x1: 64 MB
    size_t off_y2b     = a256(off_x1 + 64000000);              // bf16 y2b: 32 MB
    size_t off_stats   = a256(off_y2b + 32000000);             // 4 KB (sums1,ss1,ss2)
    size_t off_s2s     = a256(off_stats + 4096);               // 64 KB
    size_t off_countsA = a256(off_s2s + 65536);                // 4 MB  } contiguous
    size_t off_countsB = off_countsA + 4ull * NBINS_KC;        // 4 MB  } for one memset
    size_t off_kstartA = a256(off_countsB + 4ull * NBINS_KC);  // 4 MB + 4
    size_t off_kstartB = a256(off_kstartA + 4ull * (NBINS_KC + 1));
    size_t off_bsum    = a256(off_kstartB + 4ull * (NBINS_KC + 1));  // 1 KB
    size_t off_listA   = a256(off_bsum + 1024);                // 2 MB
    size_t off_listB   = a256(off_listA + 4 * NPAIRS);         // 2 MB
    size_t off_wf12    = a256(off_listB + 4 * NPAIRS);         // 256 KB
    size_t off_wfs     = a256(off_wf12 + 262144);              // 256 KB
    size_t need        = off_wfs + 262144;

    if (need > ws_size) {
        // -------- fallback: atomic path (needs only 64 MB + 4 KB) --------
        float* y1f   = (float*)ws;
        float* stats = y1f + (long)N_OUT * COUT;
        float* sums1 = stats;
        float* ss1   = stats + 128;
        float* sums2 = stats + 256;
        float* ss2   = stats + 512;

        hipMemsetAsync(d_out, 0, (size_t)N_OUT * COUT * 4, stream);
        hipMemsetAsync(d_ws,  0, (size_t)N_OUT * COUT * 4 + 768 * 4, stream);

        bn_stats_kernel<64><<<1024, 256, 0, stream>>>(x, N_IN, sums1);
        bn_finalize_kernel<64><<<1, 64, 0, stream>>>(sums1, gamma1, beta1, 1.f / N_IN, ss1);

        dim3 cgrid((R_PAIRS + OLD_TILES * 64 - 1) / (OLD_TILES * 64), K_OFF);
        conv12_atomic_kernel<<<cgrid, 256, 0, stream>>>(x, W1, W2, in_idx1, out_idx1, ss1, y1f, out);

        bn_stats_kernel<128><<<1024, 256, 0, stream>>>(y1f, N_OUT, sums2);
        bn_finalize_kernel<128><<<1, 128, 0, stream>>>(sums2, gamma2, beta2, 1.f / N_OUT, ss2);

        convs_atomic_kernel<<<cgrid, 256, 0, stream>>>(y1f, Ws, in_idx_s, out_idx_s, ss2, out);
        return;
    }

    bf16*  y1      = (bf16*)(ws + off_y1);
    bf16*  x1      = (bf16*)(ws + off_x1);
    bf16*  y2b     = (bf16*)(ws + off_y2b);
    float* sums1   = (float*)(ws + off_stats);    // [256]
    float* ss1     = sums1 + 256;                 // [256]
    float* ss2     = sums1 + 512;                 // [256]
    float* s2s     = (float*)(ws + off_s2s);      // [64][256]
    u32*   countsA = (u32*)(ws + off_countsA);
    u32*   countsB = (u32*)(ws + off_countsB);
    u32*   kstartA = (u32*)(ws + off_kstartA);
    u32*   kstartB = (u32*)(ws + off_kstartB);
    u32*   bsum    = (u32*)(ws + off_bsum);
    u32*   listA   = (u32*)(ws + off_listA);
    u32*   listB   = (u32*)(ws + off_listB);
    bf16*  wf12    = (bf16*)(ws + off_wf12);
    bf16*  wfs     = (bf16*)(ws + off_wfs);

    int nblk = (N_OUT + BM - 1) / BM;    // 3907

    // ---- init (one big memset for both hist buffers; small one for stats+s2s) ----
    hipMemsetAsync(ws + off_stats, 0, off_countsA - off_stats, stream);   // stats + s2s
    hipMemsetAsync(countsA, 0, 8ull * NBINS_KC, stream);                  // countsA+countsB

    // ---- both rulebook sorts (independent of BN pipeline) ----
    histOK_kernel<<<512, 256, 0, stream>>>(out_idx1, countsA);
    histOK_kernel<<<512, 256, 0, stream>>>(out_idx_s, countsB);
    scan1_kernel<<<NSB_KC, 256, 0, stream>>>(countsA, bsum, NBINS_KC);
    scan2_kernel<<<1, 256, 0, stream>>>(bsum, kstartA, NSB_KC, NBINS_KC);
    scan3_kernel<<<NSB_KC, 256, 0, stream>>>(countsA, bsum, kstartA, NBINS_KC);
    scan1_kernel<<<NSB_KC, 256, 0, stream>>>(countsB, bsum, NBINS_KC);
    scan2_kernel<<<1, 256, 0, stream>>>(bsum, kstartB, NSB_KC, NBINS_KC);
    scan3_kernel<<<NSB_KC, 256, 0, stream>>>(countsB, bsum, kstartB, NBINS_KC);
    buildF_kernel<<<(NPAIRS + 255) / 256, 256, 0, stream>>>(in_idx1, out_idx1, kstartA, countsA, listA);
    buildF_kernel<<<(NPAIRS + 255) / 256, 256, 0, stream>>>(in_idx_s, out_idx_s, kstartB, countsB, listB);

    // ---- BN1 stats + apply -> x1 (bf16); weight prepack ----
    bn_stats_kernel<64><<<1024, 256, 0, stream>>>(x, N_IN, sums1);
    bn_finalize_kernel<64><<<1, 64, 0, stream>>>(sums1, gamma1, beta1, 1.f / N_IN, ss1);
    bn_apply_f32_kernel<64><<<4096, 256, 0, stream>>>(x, ss1, x1, (long)N_IN * CIN / 8);
    pack12_kernel<<<512, 256, 0, stream>>>(W1, W2, wf12);
    packS_kernel<<<512, 256, 0, stream>>>(Ws, wfs);

    // ---- fused conv1+conv2 ----
    fused12_kernel<<<nblk, 256, 0, stream>>>(x1, wf12, kstartA, listA, y1, y2b, s2s);
    bn_finalize2_kernel<<<1, 128, 0, stream>>>(s2s, gamma2, beta2, ss2);

    // ---- fused submanifold conv (BN2+ReLU in reduce, +y2b epilogue) ----
    fusedS_kernel<<<nblk, 256, 0, stream>>>(y1, wfs, ss2, kstartB, listB, y2b, out);
}

// Round 12
// 392.744 us; speedup vs baseline: 1.3031x; 1.3031x over previous
//
#include <hip/hip_runtime.h>

#define K_OFF   8
#define R_PAIRS 62500
#define NPAIRS  500000
#define N_IN    500000
#define N_OUT   125000
#define CIN     64
#define COUT    128
#define BN_EPS  1e-4f
#define SCAN_ELEMS 4096
#define NBINS_KC (N_OUT * K_OFF)     // 1,000,000
#define NSB_KC  245                  // ceil(1e6 / 4096)
#define BM      32
#define CHUNK   64
#define OLD_TILES 8

typedef __bf16 bf16;
typedef __bf16 bf16x4 __attribute__((ext_vector_type(4)));
typedef __bf16 bf16x8 __attribute__((ext_vector_type(8)));
typedef float  f32x4  __attribute__((ext_vector_type(4)));
typedef unsigned int u32;

// bf16-z byte-offset swizzle: row-stride 1024B, inject row low bits into 16B-slot bits.
__device__ __forceinline__ int zb(int row, int col_bf16) {
    int byte = (row << 10) + (col_bf16 << 1);
    return byte ^ ((row & 7) << 4);
}

// ==================== BN statistics ====================
template<int C>
__global__ void bn_stats_kernel(const float* __restrict__ x, int n_rows,
                                float* __restrict__ sums /* [2C] */) {
    constexpr int CG = C / 4;
    int tid = blockIdx.x * blockDim.x + threadIdx.x;
    int nth = gridDim.x * blockDim.x;
    const float4* x4 = (const float4*)x;
    long n4 = (long)n_rows * CG;
    int cg = tid % CG;
    float s[4] = {0,0,0,0}, q[4] = {0,0,0,0};
    for (long i = tid; i < n4; i += nth) {
        float4 v = x4[i];
        float f[4] = {v.x, v.y, v.z, v.w};
        #pragma unroll
        for (int j = 0; j < 4; j++) { s[j] += f[j]; q[j] += f[j] * f[j]; }
    }
    __shared__ float acc[2 * C];
    for (int i = threadIdx.x; i < 2 * C; i += blockDim.x) acc[i] = 0.f;
    __syncthreads();
    #pragma unroll
    for (int j = 0; j < 4; j++) {
        atomicAdd(&acc[cg * 4 + j], s[j]);
        atomicAdd(&acc[C + cg * 4 + j], q[j]);
    }
    __syncthreads();
    for (int i = threadIdx.x; i < 2 * C; i += blockDim.x) atomicAdd(&sums[i], acc[i]);
}

template<int C>
__global__ void bn_finalize_kernel(const float* __restrict__ sums,
                                   const float* __restrict__ gamma,
                                   const float* __restrict__ beta,
                                   float inv_n, float* __restrict__ ss) {
    int c = threadIdx.x;
    if (c < C) {
        float m  = sums[c] * inv_n;
        float v  = sums[C + c] * inv_n - m * m;
        float sc = gamma[c] * rsqrtf(v + BN_EPS);
        ss[c]     = sc;
        ss[C + c] = beta[c] - m * sc;
    }
}

// BN2 finalize from 64 striped partial-sum copies
__global__ void bn_finalize2_kernel(const float* __restrict__ S /*[64][256]*/,
                                    const float* __restrict__ gamma,
                                    const float* __restrict__ beta,
                                    float* __restrict__ ss) {
    int c = threadIdx.x;   // 128
    float s = 0.f, q = 0.f;
    for (int st = 0; st < 64; st++) { s += S[st * 256 + c]; q += S[st * 256 + 128 + c]; }
    float m = s / (float)N_OUT;
    float v = q / (float)N_OUT - m * m;
    float sc = gamma[c] * rsqrtf(v + BN_EPS);
    ss[c] = sc; ss[128 + c] = beta[c] - m * sc;
}

// ==================== weight prepack (fragment order) ====================
__global__ void pack12_kernel(const float* __restrict__ W1, const float* __restrict__ W2,
                              bf16* __restrict__ Wf) {
    int idx = blockIdx.x * 256 + threadIdx.x;      // 131072
    int j = idx & 7;
    int lane = (idx >> 3) & 63;
    int fi = idx >> 9;            // 0..255
    int ks = fi >> 4, nfrag = fi & 15;
    int k512 = ks * 32 + (lane >> 4) * 8 + j;
    int koff = k512 >> 6, kc = k512 & 63;
    int c = nfrag * 16 + (lane & 15);
    const float* W = (c < 128) ? W1 : W2;
    Wf[idx] = (bf16)W[((long)koff * CIN + kc) * COUT + (c & 127)];
}

__global__ void packS_kernel(const float* __restrict__ Ws, bf16* __restrict__ Wf) {
    int idx = blockIdx.x * 256 + threadIdx.x;      // 131072
    int j = idx & 7;
    int lane = (idx >> 3) & 63;
    int fi = idx >> 9;            // 0..255
    int ksg = fi >> 3, nfrag = fi & 7;
    int k1024 = ksg * 32 + (lane >> 4) * 8 + j;
    int koff = k1024 >> 7, kc = k1024 & 127;
    int c = nfrag * 16 + (lane & 15);
    Wf[idx] = (bf16)Ws[((long)koff * COUT + kc) * COUT + c];
}

// ==================== hist over (out,k) bins ====================
__global__ void histOK_kernel(const int* __restrict__ oidx, u32* __restrict__ counts) {
    int p = blockIdx.x * blockDim.x + threadIdx.x;
    int stride = gridDim.x * blockDim.x;
    for (; p < NPAIRS; p += stride) {
        int bin = oidx[p] * K_OFF + p / R_PAIRS;
        atomicAdd(&counts[bin], 1u);
    }
}

// ==================== 3-level scan ====================
__global__ void scan1_kernel(const u32* __restrict__ counts, u32* __restrict__ bsum, int n) {
    __shared__ u32 sd[256];
    int tid = threadIdx.x;
    int base = blockIdx.x * SCAN_ELEMS + tid * 16;
    u32 s = 0;
    #pragma unroll
    for (int j = 0; j < 16; j++) { int i = base + j; if (i < n) s += counts[i]; }
    sd[tid] = s; __syncthreads();
    for (int st = 128; st > 0; st >>= 1) { if (tid < st) sd[tid] += sd[tid + st]; __syncthreads(); }
    if (tid == 0) bsum[blockIdx.x] = sd[0];
}

__global__ void scan2_kernel(u32* __restrict__ bsum, u32* __restrict__ starts, int nb, int n) {
    __shared__ u32 sd[256];
    int tid = threadIdx.x;
    u32 v = (tid < nb) ? bsum[tid] : 0;
    sd[tid] = v; __syncthreads();
    for (int st = 1; st < 256; st <<= 1) {
        u32 t = (tid >= st) ? sd[tid - st] : 0;
        __syncthreads();
        sd[tid] += t;
        __syncthreads();
    }
    if (tid < nb) bsum[tid] = sd[tid] - v;     // exclusive
    if (tid == 255) starts[n] = sd[255];       // total
}

__global__ void scan3_kernel(const u32* __restrict__ counts, const u32* __restrict__ bsum,
                             u32* __restrict__ starts, int n) {
    __shared__ u32 sd[256];
    int tid = threadIdx.x;
    int base = blockIdx.x * SCAN_ELEMS + tid * 16;
    u32 v[16]; u32 s = 0;
    #pragma unroll
    for (int j = 0; j < 16; j++) { int i = base + j; v[j] = (i < n) ? counts[i] : 0; s += v[j]; }
    sd[tid] = s; __syncthreads();
    for (int st = 1; st < 256; st <<= 1) {
        u32 t = (tid >= st) ? sd[tid - st] : 0;
        __syncthreads();
        sd[tid] += t;
        __syncthreads();
    }
    u32 run = bsum[blockIdx.x] + sd[tid] - s;
    #pragma unroll
    for (int j = 0; j < 16; j++) { int i = base + j; if (i < n) starts[i] = run; run += v[j]; }
}

// ==================== build (out,k)-sorted gather list (cursor = counts, atomicSub) ==
__global__ void buildF_kernel(const int* __restrict__ iidx, const int* __restrict__ oidx,
                              const u32* __restrict__ kstart, u32* __restrict__ counts,
                              u32* __restrict__ listF) {
    int p = blockIdx.x * 256 + threadIdx.x;
    if (p >= NPAIRS) return;
    int bin = oidx[p] * K_OFF + p / R_PAIRS;
    u32 c = atomicSub(&counts[bin], 1u);
    listF[kstart[bin] + c - 1u] = (u32)iidx[p];
}

// ==================== fused conv1+conv2: chunked coalesced stage + owner reduce =====
// 512 threads. Block = 32 out rows = contiguous listF span [lo,hi).
// Stage: 16 thr/entry read x row (256B fp32) coalesced, BN1+ReLU -> As bf16 [64][64].
// Owner: thread (row=tid>>4, sl=tid&15) owns k=sl>>1, ch slice (sl&1)*32: reads its
// segment's chunk-overlap from As (slots = p - cb). z [32][512] bf16 -> GEMM 8 waves.
__global__ __launch_bounds__(512) void fused12_kernel(
    const float* __restrict__ x, const bf16* __restrict__ Wf, const float* __restrict__ ss1,
    const u32* __restrict__ kstart, const u32* __restrict__ listF,
    bf16* __restrict__ y1, bf16* __restrict__ y2b, float* __restrict__ sums2s)
{
    __shared__ bf16 z[BM * 512];      // 32 KB
    __shared__ bf16 As[CHUNK * 64];   // 8 KB
    __shared__ float s_sc[64], s_sh[64];
    int tid = threadIdx.x, lane = tid & 63, wave = tid >> 6;
    int o0 = blockIdx.x * BM;
    int nrow = min(BM, N_OUT - o0);
    if (tid < 64) { s_sc[tid] = ss1[tid]; s_sh[tid] = ss1[64 + tid]; }

    int row = tid >> 4, sl = tid & 15;
    int ch0 = (sl & 1) * 32;
    u32 sA = 0, eA = 0;
    if (row < nrow) {
        size_t bin = (size_t)(o0 + row) * K_OFF + (sl >> 1);
        sA = kstart[bin]; eA = kstart[bin + 1];
    }
    u32 lo  = kstart[(size_t)o0 * K_OFF];
    u32 hiS = kstart[(size_t)(o0 + nrow) * K_OFF];

    f32x4 a[8];
    #pragma unroll
    for (int g = 0; g < 8; g++) a[g] = (f32x4)(0.f);

    for (u32 cb = lo; cb < hiS; cb += CHUNK) {
        u32 cEnd = min(cb + (u32)CHUNK, hiS);
        int nE = (int)(cEnd - cb);
        __syncthreads();              // As free; s_sc ready on first iter
        #pragma unroll
        for (int r = 0; r < 2; r++) { // 32 entries per round, 16 thr/entry
            int slot = r * 32 + (tid >> 4);
            if (slot < nE) {
                u32 in = listF[cb + slot];
                int cpos = (tid & 15) * 4;
                float4 v = *(const float4*)(x + (size_t)in * 64 + cpos);
                float f[4] = {v.x, v.y, v.z, v.w};
                bf16x4 h;
                #pragma unroll
                for (int j = 0; j < 4; j++)
                    h[j] = (bf16)fmaxf(f[j] * s_sc[cpos + j] + s_sh[cpos + j], 0.f);
                *(bf16x4*)((char*)As + ((slot * 128 + cpos * 2) ^ ((slot & 7) << 4))) = h;
            }
        }
        __syncthreads();
        u32 pa = max(sA, cb), pb = min(eA, cEnd);
        for (u32 p = pa; p < pb; p++) {
            int slot = (int)(p - cb);
            #pragma unroll
            for (int u = 0; u < 4; u++) {
                int bo = (slot * 128 + ch0 * 2 + u * 16) ^ ((slot & 7) << 4);
                int4 vi = *(const int4*)((const char*)As + bo);
                bf16x8 hv = *(bf16x8*)&vi;
                #pragma unroll
                for (int j = 0; j < 8; j++)
                    a[u * 2 + (j >> 2)][j & 3] += (float)hv[j];
            }
        }
    }
    __syncthreads();

    // z write (full coverage: 32 rows x 16 slices)
    {
        int colb = sl * 32;   // == (sl>>1)*64 + (sl&1)*32
        #pragma unroll
        for (int u = 0; u < 4; u++) {
            bf16x8 h;
            #pragma unroll
            for (int j = 0; j < 8; j++) h[j] = (bf16)a[u * 2 + (j >> 2)][j & 3];
            *(bf16x8*)((char*)z + zb(row, colb + u * 8)) = h;
        }
    }
    __syncthreads();

    // ---- GEMM [32 x 512] x [512 x 256], 8 waves: wave -> cat cols wave*32..+32 ----
    int l15 = lane & 15, kr0 = (lane >> 4) * 8;
    f32x4 acc[2][2];
    #pragma unroll
    for (int m = 0; m < 2; m++)
        #pragma unroll
        for (int nf = 0; nf < 2; nf++) acc[m][nf] = (f32x4)(0.f);

    for (int ks = 0; ks < 16; ks++) {
        int colb = ks * 32 + kr0;
        bf16x8 af0 = *(bf16x8*)((char*)z + zb(l15, colb));
        bf16x8 af1 = *(bf16x8*)((char*)z + zb(l15 + 16, colb));
        #pragma unroll
        for (int nf = 0; nf < 2; nf++) {
            bf16x8 bf = *(const bf16x8*)(Wf + ((size_t)(ks * 16 + wave * 2 + nf) * 64 + lane) * 8);
            acc[0][nf] = __builtin_amdgcn_mfma_f32_16x16x32_bf16(af0, bf, acc[0][nf], 0, 0, 0);
            acc[1][nf] = __builtin_amdgcn_mfma_f32_16x16x32_bf16(af1, bf, acc[1][nf], 0, 0, 0);
        }
    }
    __syncthreads();   // z reads done -> reuse as stage

    // stage bf16 [32 rows][256 cat cols] (16 KB)
    bf16* st = z;
    int rb = (lane >> 4) * 4;
    #pragma unroll
    for (int m = 0; m < 2; m++)
        #pragma unroll
        for (int nf = 0; nf < 2; nf++)
            #pragma unroll
            for (int j = 0; j < 4; j++)
                st[(m * 16 + rb + j) * 256 + wave * 32 + nf * 16 + l15] = (bf16)acc[m][nf][j];
    __syncthreads();

    // BN2 stats over y1 cols (0..127), striped atomics
    if (tid < 128) {
        float s = 0.f, q = 0.f;
        for (int r = 0; r < nrow; r++) { float v = (float)st[r * 256 + tid]; s += v; q += v * v; }
        int sb = (blockIdx.x & 63) * 256;
        atomicAdd(&sums2s[sb + tid], s);
        atomicAdd(&sums2s[sb + 128 + tid], q);
    }
    // output: 512 threads = 32 rows x 16 segs
    {
        int orow = tid >> 4, seg = tid & 15;
        if (orow < nrow) {
            const int4* src = (const int4*)(st + orow * 256 + seg * 16);
            int4 v0 = src[0], v1 = src[1];
            bf16* dst = (seg < 8) ? (y1  + (size_t)(o0 + orow) * 128 + seg * 16)
                                  : (y2b + (size_t)(o0 + orow) * 128 + (seg - 8) * 16);
            ((int4*)dst)[0] = v0; ((int4*)dst)[1] = v1;
        }
    }
}

// ==================== fused submanifold conv: chunked stage + owner reduce =========
// 512 threads. Stage: 16 thr/entry read y1 row (256B bf16), BN2+ReLU -> As [64][128].
// Owner (row, sl): ch slice (sl&3)*32, bins k=sl>>2 (aA) and 4+(sl>>2) (aB), both
// accumulated in the SAME chunk pass. Two K=512 GEMM halves share z.
__global__ __launch_bounds__(512) void fusedS_kernel(
    const bf16* __restrict__ y1, const bf16* __restrict__ Wf, const float* __restrict__ ss2,
    const u32* __restrict__ kstart, const u32* __restrict__ listF,
    const bf16* __restrict__ y2b, float* __restrict__ out)
{
    __shared__ bf16 z[BM * 512];       // 32 KB
    __shared__ bf16 As[CHUNK * 128];   // 16 KB
    __shared__ float s_sc[128], s_sh[128];
    int tid = threadIdx.x, lane = tid & 63, wave = tid >> 6;
    int o0 = blockIdx.x * BM;
    int nrow = min(BM, N_OUT - o0);
    if (tid < 128) { s_sc[tid] = ss2[tid]; s_sh[tid] = ss2[128 + tid]; }

    int row = tid >> 4, sl = tid & 15;
    int kq = sl >> 2, ch0 = (sl & 3) * 32;
    u32 sA = 0, eA = 0, sB = 0, eB = 0;
    if (row < nrow) {
        size_t binb = (size_t)(o0 + row) * K_OFF;
        sA = kstart[binb + kq];     eA = kstart[binb + kq + 1];
        sB = kstart[binb + 4 + kq]; eB = kstart[binb + 4 + kq + 1];
    }
    u32 lo  = kstart[(size_t)o0 * K_OFF];
    u32 hiS = kstart[(size_t)(o0 + nrow) * K_OFF];

    f32x4 aA[8], aB[8];
    #pragma unroll
    for (int g = 0; g < 8; g++) { aA[g] = (f32x4)(0.f); aB[g] = (f32x4)(0.f); }

    for (u32 cb = lo; cb < hiS; cb += CHUNK) {
        u32 cEnd = min(cb + (u32)CHUNK, hiS);
        int nE = (int)(cEnd - cb);
        __syncthreads();              // As free; s_sc ready on first iter
        #pragma unroll
        for (int r = 0; r < 2; r++) { // 32 entries per round, 16 thr/entry
            int slot = r * 32 + (tid >> 4);
            if (slot < nE) {
                u32 in = listF[cb + slot];
                int cpos = (tid & 15) * 8;
                int4 vi = *(const int4*)(y1 + (size_t)in * 128 + cpos);
                bf16x8 hv = *(bf16x8*)&vi;
                bf16x8 ho;
                #pragma unroll
                for (int j = 0; j < 8; j++)
                    ho[j] = (bf16)fmaxf((float)hv[j] * s_sc[cpos + j] + s_sh[cpos + j], 0.f);
                *(bf16x8*)((char*)As + ((slot * 256 + cpos * 2) ^ ((slot & 7) << 4))) = ho;
            }
        }
        __syncthreads();
        // owner reduce: both halves from this chunk
        u32 pa = max(sA, cb), pb = min(eA, cEnd);
        for (u32 p = pa; p < pb; p++) {
            int slot = (int)(p - cb);
            #pragma unroll
            for (int u = 0; u < 4; u++) {
                int bo = (slot * 256 + ch0 * 2 + u * 16) ^ ((slot & 7) << 4);
                int4 vi = *(const int4*)((const char*)As + bo);
                bf16x8 hv = *(bf16x8*)&vi;
                #pragma unroll
                for (int j = 0; j < 8; j++)
                    aA[u * 2 + (j >> 2)][j & 3] += (float)hv[j];
            }
        }
        pa = max(sB, cb); pb = min(eB, cEnd);
        for (u32 p = pa; p < pb; p++) {
            int slot = (int)(p - cb);
            #pragma unroll
            for (int u = 0; u < 4; u++) {
                int bo = (slot * 256 + ch0 * 2 + u * 16) ^ ((slot & 7) << 4);
                int4 vi = *(const int4*)((const char*)As + bo);
                bf16x8 hv = *(bf16x8*)&vi;
                #pragma unroll
                for (int j = 0; j < 8; j++)
                    aB[u * 2 + (j >> 2)][j & 3] += (float)hv[j];
            }
        }
    }

    int l15 = lane & 15, kr0 = (lane >> 4) * 8;
    f32x4 acc[2];
    acc[0] = (f32x4)(0.f); acc[1] = (f32x4)(0.f);
    int colb0 = sl * 32;   // == kq*128 + ch0

    #pragma unroll
    for (int h = 0; h < 2; h++) {
        __syncthreads();   // h=0: reduce done; h=1: GEMM h=0 z reads done
        {
            #pragma unroll
            for (int u = 0; u < 4; u++) {
                bf16x8 hv;
                #pragma unroll
                for (int j = 0; j < 8; j++)
                    hv[j] = (bf16)((h == 0 ? aA : aB)[u * 2 + (j >> 2)][j & 3]);
                *(bf16x8*)((char*)z + zb(row, colb0 + u * 8)) = hv;
            }
        }
        __syncthreads();

        for (int ks = 0; ks < 16; ks++) {
            int colb = ks * 32 + kr0;
            bf16x8 af0 = *(bf16x8*)((char*)z + zb(l15, colb));
            bf16x8 af1 = *(bf16x8*)((char*)z + zb(l15 + 16, colb));
            int fi = (h * 16 + ks) * 8 + wave;
            bf16x8 bf = *(const bf16x8*)(Wf + ((size_t)fi * 64 + lane) * 8);
            acc[0] = __builtin_amdgcn_mfma_f32_16x16x32_bf16(af0, bf, acc[0], 0, 0, 0);
            acc[1] = __builtin_amdgcn_mfma_f32_16x16x32_bf16(af1, bf, acc[1], 0, 0, 0);
        }
    }
    __syncthreads();

    // stage fp32 [32][128] (16 KB, inside z)
    float* zf = (float*)z;
    int rb = (lane >> 4) * 4;
    #pragma unroll
    for (int m = 0; m < 2; m++)
        #pragma unroll
        for (int j = 0; j < 4; j++)
            zf[(m * 16 + rb + j) * 128 + wave * 16 + l15] = acc[m][j];
    __syncthreads();

    {
        int orow = tid >> 4, seg = tid & 15;   // 8 floats each
        if (orow < nrow) {
            f32x4 s0 = *(f32x4*)&zf[orow * 128 + seg * 8];
            f32x4 s1 = *(f32x4*)&zf[orow * 128 + seg * 8 + 4];
            int4 yv = *(const int4*)(y2b + (size_t)(o0 + orow) * 128 + seg * 8);
            bf16x8 hy = *(bf16x8*)&yv;
            float4 w0 = make_float4(s0[0] + (float)hy[0], s0[1] + (float)hy[1],
                                    s0[2] + (float)hy[2], s0[3] + (float)hy[3]);
            float4 w1 = make_float4(s1[0] + (float)hy[4], s1[1] + (float)hy[5],
                                    s1[2] + (float)hy[6], s1[3] + (float)hy[7]);
            float* dst = out + (size_t)(o0 + orow) * 128 + seg * 8;
            *(float4*)dst = w0;
            *(float4*)(dst + 4) = w1;
        }
    }
}

// ==================== fallback (round-1 atomic path) ====================
__global__ __launch_bounds__(256) void conv12_atomic_kernel(
    const float* __restrict__ x,
    const float* __restrict__ W1, const float* __restrict__ W2,
    const int* __restrict__ in_idx, const int* __restrict__ out_idx,
    const float* __restrict__ ss1,
    float* __restrict__ y1, float* __restrict__ y2)
{
    int k    = blockIdx.y;
    int tid  = threadIdx.x;
    int wave = tid >> 6, lane = tid & 63;

    __shared__ bf16 As[64 * 64];
    __shared__ int  s_out[64];
    __shared__ float s_sc[64], s_sh[64];
    char* asb = (char*)As;

    if (tid < 64) { s_sc[tid] = ss1[tid]; s_sh[tid] = ss1[64 + tid]; }

    const float* Wk = ((wave & 2) ? W2 : W1) + (long)k * CIN * COUT;
    int nbase = (wave & 1) * 64;
    int l15 = lane & 15;
    int kr0 = (lane >> 4) * 8;

    bf16x8 bfrag[2][4];
    #pragma unroll
    for (int ks = 0; ks < 2; ks++)
        #pragma unroll
        for (int nf = 0; nf < 4; nf++) {
            const float* p = Wk + (long)(ks * 32 + kr0) * COUT + nbase + nf * 16 + l15;
            bf16x8 b;
            #pragma unroll
            for (int j = 0; j < 8; j++) b[j] = (bf16)p[(long)j * COUT];
            bfrag[ks][nf] = b;
        }

    const int* in_k  = in_idx  + k * R_PAIRS;
    const int* out_k = out_idx + k * R_PAIRS;
    float* ybase = (wave & 2) ? y2 : y1;

    int grow = tid >> 2;
    int gcol = (tid & 3) * 16;

    __syncthreads();

    for (int t = 0; t < OLD_TILES; t++) {
        int pair0 = blockIdx.x * (OLD_TILES * 64) + t * 64;
        {
            int p = pair0 + grow;
            bool valid = p < R_PAIRS;
            long src = valid ? (long)in_k[p] : 0;
            const float4* xr = (const float4*)(x + src * CIN + gcol);
            #pragma unroll
            for (int g = 0; g < 2; g++) {
                float4 va = make_float4(0, 0, 0, 0), vb = va;
                if (valid) { va = xr[g * 2]; vb = xr[g * 2 + 1]; }
                float f[8] = {va.x, va.y, va.z, va.w, vb.x, vb.y, vb.z, vb.w};
                bf16x8 h;
                #pragma unroll
                for (int j = 0; j < 8; j++) {
                    int c = gcol + g * 8 + j;
                    h[j] = (bf16)fmaxf(f[j] * s_sc[c] + s_sh[c], 0.f);
                }
                int boff = ((grow * 128) + (gcol + g * 8) * 2) ^ ((grow & 7) << 4);
                *(bf16x8*)(asb + boff) = h;
            }
        }
        if (tid < 64) {
            int p = pair0 + tid;
            s_out[tid] = (p < R_PAIRS) ? out_k[p] : -1;
        }
        __syncthreads();

        f32x4 acc[4][4];
        #pragma unroll
        for (int m = 0; m < 4; m++)
            #pragma unroll
            for (int n = 0; n < 4; n++) acc[m][n] = (f32x4)(0.f);

        #pragma unroll
        for (int ks = 0; ks < 2; ks++) {
            bf16x8 af[4];
            #pragma unroll
            for (int m = 0; m < 4; m++) {
                int rrow = m * 16 + l15;
                int boff = (rrow * 128 + (ks * 32 + kr0) * 2) ^ ((rrow & 7) << 4);
                af[m] = *(bf16x8*)(asb + boff);
            }
            #pragma unroll
            for (int m = 0; m < 4; m++)
                #pragma unroll
                for (int nf = 0; nf < 4; nf++)
                    acc[m][nf] = __builtin_amdgcn_mfma_f32_16x16x32_bf16(
                        af[m], bfrag[ks][nf], acc[m][nf], 0, 0, 0);
        }

        int rbase = (lane >> 4) * 4;
        #pragma unroll
        for (int m = 0; m < 4; m++)
            #pragma unroll
            for (int j = 0; j < 4; j++) {
                int o = s_out[m * 16 + rbase + j];
                if (o >= 0)
                    #pragma unroll
                    for (int nf = 0; nf < 4; nf++)
                        atomicAdd(&ybase[(long)o * COUT + nbase + nf * 16 + l15],
                                  acc[m][nf][j]);
            }
        __syncthreads();
    }
}

__global__ __launch_bounds__(256) void convs_atomic_kernel(
    const float* __restrict__ y1,
    const float* __restrict__ Ws,
    const int* __restrict__ in_idx, const int* __restrict__ out_idx,
    const float* __restrict__ ss2,
    float* __restrict__ out)
{
    int k    = blockIdx.y;
    int tid  = threadIdx.x;
    int wave = tid >> 6, lane = tid & 63;

    __shared__ bf16 As[64 * 128];
    __shared__ int  s_out[64];
    __shared__ float s_sc[128], s_sh[128];
    char* asb = (char*)As;

    if (tid < 128) { s_sc[tid] = ss2[tid]; s_sh[tid] = ss2[128 + tid]; }

    const float* Wk = Ws + (long)k * COUT * COUT;
    int nbase = wave * 32;
    int l15 = lane & 15;
    int kr0 = (lane >> 4) * 8;

    bf16x8 bfrag[4][2];
    #pragma unroll
    for (int ks = 0; ks < 4; ks++)
        #pragma unroll
        for (int nf = 0; nf < 2; nf++) {
            const float* p = Wk + (long)(ks * 32 + kr0) * COUT + nbase + nf * 16 + l15;
            bf16x8 b;
            #pragma unroll
            for (int j = 0; j < 8; j++) b[j] = (bf16)p[(long)j * COUT];
            bfrag[ks][nf] = b;
        }

    const int* in_k  = in_idx  + k * R_PAIRS;
    const int* out_k = out_idx + k * R_PAIRS;

    int grow = tid >> 2;
    int gcol = (tid & 3) * 32;

    __syncthreads();

    for (int t = 0; t < OLD_TILES; t++) {
        int pair0 = blockIdx.x * (OLD_TILES * 64) + t * 64;
        {
            int p = pair0 + grow;
            bool valid = p < R_PAIRS;
            long src = valid ? (long)in_k[p] : 0;
            const float4* yr = (const float4*)(y1 + src * COUT + gcol);
            #pragma unroll
            for (int g = 0; g < 4; g++) {
                float4 va = make_float4(0, 0, 0, 0), vb = va;
                if (valid) { va = yr[g * 2]; vb = yr[g * 2 + 1]; }
                float f[8] = {va.x, va.y, va.z, va.w, vb.x, vb.y, vb.z, vb.w};
                bf16x8 h;
                #pragma unroll
                for (int j = 0; j < 8; j++) {
                    int c = gcol + g * 8 + j;
                    h[j] = (bf16)fmaxf(f[j] * s_sc[c] + s_sh[c], 0.f);
                }
                int boff = (grow * 256 + (gcol + g * 8) * 2) ^ ((grow & 7) << 4);
                *(bf16x8*)(asb + boff) = h;
            }
        }
        if (tid < 64) {
            int p = pair0 + tid;
            s_out[tid] = (p < R_PAIRS) ? out_k[p] : -1;
        }
        __syncthreads();

        f32x4 acc[4][2];
        #pragma unroll
        for (int m = 0; m < 4; m++)
            #pragma unroll
            for (int n = 0; n < 2; n++) acc[m][n] = (f32x4)(0.f);

        #pragma unroll
        for (int ks = 0; ks < 4; ks++) {
            bf16x8 af[4];
            #pragma unroll
            for (int m = 0; m < 4; m++) {
                int rrow = m * 16 + l15;
                int boff = (rrow * 256 + (ks * 32 + kr0) * 2) ^ ((rrow & 7) << 4);
                af[m] = *(bf16x8*)(asb + boff);
            }
            #pragma unroll
            for (int m = 0; m < 4; m++)
                #pragma unroll
                for (int nf = 0; nf < 2; nf++)
                    acc[m][nf] = __builtin_amdgcn_mfma_f32_16x16x32_bf16(
                        af[m], bfrag[ks][nf], acc[m][nf], 0, 0, 0);
        }

        int rbase = (lane >> 4) * 4;
        #pragma unroll
        for (int m = 0; m < 4; m++)
            #pragma unroll
            for (int j = 0; j < 4; j++) {
                int o = s_out[m * 16 + rbase + j];
                if (o >= 0)
                    #pragma unroll
                    for (int nf = 0; nf < 2; nf++)
                        atomicAdd(&out[(long)o * COUT + nbase + nf * 16 + l15],
                                  acc[m][nf][j]);
            }
        __syncthreads();
    }
}

// ==================== host ====================
extern "C" void kernel_launch(void* const* d_in, const int* in_sizes, int n_in,
                              void* d_out, int out_size, void* d_ws, size_t ws_size,
                              hipStream_t stream) {
    const float* x       = (const float*)d_in[0];
    const float* gamma1  = (const float*)d_in[1];
    const float* beta1   = (const float*)d_in[2];
    const float* gamma2  = (const float*)d_in[3];
    const float* beta2   = (const float*)d_in[4];
    const float* W1      = (const float*)d_in[5];
    const float* Ws      = (const float*)d_in[6];
    const float* W2      = (const float*)d_in[7];
    const int*   in_idx1   = (const int*)d_in[8];
    const int*   out_idx1  = (const int*)d_in[9];
    const int*   in_idx_s  = (const int*)d_in[10];
    const int*   out_idx_s = (const int*)d_in[11];

    float* out = (float*)d_out;
    char*  ws  = (char*)d_ws;

    auto a256 = [](size_t v) { return (v + 255) & ~(size_t)255; };

    size_t off_y1      = 0;                                    // bf16 y1: 32 MB
    size_t off_y2b     = a256(off_y1 + 32000000);              // bf16 y2b: 32 MB
    size_t off_stats   = a256(off_y2b + 32000000);             // 4 KB (sums1,ss1,ss2)
    size_t off_s2s     = a256(off_stats + 4096);               // 64 KB
    size_t off_countsA = a256(off_s2s + 65536);                // 4 MB  } contiguous
    size_t off_countsB = off_countsA + 4ull * NBINS_KC;        // 4 MB  } for one memset
    size_t off_kstartA = a256(off_countsB + 4ull * NBINS_KC);  // 4 MB + 4
    size_t off_kstartB = a256(off_kstartA + 4ull * (NBINS_KC + 1));
    size_t off_bsum    = a256(off_kstartB + 4ull * (NBINS_KC + 1));  // 1 KB
    size_t off_listA   = a256(off_bsum + 1024);                // 2 MB
    size_t off_listB   = a256(off_listA + 4 * NPAIRS);         // 2 MB
    size_t off_wf12    = a256(off_listB + 4 * NPAIRS);         // 256 KB
    size_t off_wfs     = a256(off_wf12 + 262144);              // 256 KB
    size_t need        = off_wfs + 262144;

    if (need > ws_size) {
        // -------- fallback: atomic path (needs only 64 MB + 4 KB) --------
        float* y1f   = (float*)ws;
        float* stats = y1f + (long)N_OUT * COUT;
        float* sums1 = stats;
        float* ss1   = stats + 128;
        float* sums2 = stats + 256;
        float* ss2   = stats + 512;

        hipMemsetAsync(d_out, 0, (size_t)N_OUT * COUT * 4, stream);
        hipMemsetAsync(d_ws,  0, (size_t)N_OUT * COUT * 4 + 768 * 4, stream);

        bn_stats_kernel<64><<<1024, 256, 0, stream>>>(x, N_IN, sums1);
        bn_finalize_kernel<64><<<1, 64, 0, stream>>>(sums1, gamma1, beta1, 1.f / N_IN, ss1);

        dim3 cgrid((R_PAIRS + OLD_TILES * 64 - 1) / (OLD_TILES * 64), K_OFF);
        conv12_atomic_kernel<<<cgrid, 256, 0, stream>>>(x, W1, W2, in_idx1, out_idx1, ss1, y1f, out);

        bn_stats_kernel<128><<<1024, 256, 0, stream>>>(y1f, N_OUT, sums2);
        bn_finalize_kernel<128><<<1, 128, 0, stream>>>(sums2, gamma2, beta2, 1.f / N_OUT, ss2);

        convs_atomic_kernel<<<cgrid, 256, 0, stream>>>(y1f, Ws, in_idx_s, out_idx_s, ss2, out);
        return;
    }

    bf16*  y1      = (bf16*)(ws + off_y1);
    bf16*  y2b     = (bf16*)(ws + off_y2b);
    float* sums1   = (float*)(ws + off_stats);    // [256]
    float* ss1     = sums1 + 256;                 // [256]
    float* ss2     = sums1 + 512;                 // [256]
    float* s2s     = (float*)(ws + off_s2s);      // [64][256]
    u32*   countsA = (u32*)(ws + off_countsA);
    u32*   countsB = (u32*)(ws + off_countsB);
    u32*   kstartA = (u32*)(ws + off_kstartA);
    u32*   kstartB = (u32*)(ws + off_kstartB);
    u32*   bsum    = (u32*)(ws + off_bsum);
    u32*   listA   = (u32*)(ws + off_listA);
    u32*   listB   = (u32*)(ws + off_listB);
    bf16*  wf12    = (bf16*)(ws + off_wf12);
    bf16*  wfs     = (bf16*)(ws + off_wfs);

    int nblk = (N_OUT + BM - 1) / BM;    // 3907

    // ---- init ----
    hipMemsetAsync(ws + off_stats, 0, off_countsA - off_stats, stream);   // stats + s2s
    hipMemsetAsync(countsA, 0, 8ull * NBINS_KC, stream);                  // countsA+countsB

    // ---- both rulebook sorts ----
    histOK_kernel<<<512, 256, 0, stream>>>(out_idx1, countsA);
    histOK_kernel<<<512, 256, 0, stream>>>(out_idx_s, countsB);
    scan1_kernel<<<NSB_KC, 256, 0, stream>>>(countsA, bsum, NBINS_KC);
    scan2_kernel<<<1, 256, 0, stream>>>(bsum, kstartA, NSB_KC, NBINS_KC);
    scan3_kernel<<<NSB_KC, 256, 0, stream>>>(countsA, bsum, kstartA, NBINS_KC);
    scan1_kernel<<<NSB_KC, 256, 0, stream>>>(countsB, bsum, NBINS_KC);
    scan2_kernel<<<1, 256, 0, stream>>>(bsum, kstartB, NSB_KC, NBINS_KC);
    scan3_kernel<<<NSB_KC, 256, 0, stream>>>(countsB, bsum, kstartB, NBINS_KC);
    buildF_kernel<<<(NPAIRS + 255) / 256, 256, 0, stream>>>(in_idx1, out_idx1, kstartA, countsA, listA);
    buildF_kernel<<<(NPAIRS + 255) / 256, 256, 0, stream>>>(in_idx_s, out_idx_s, kstartB, countsB, listB);

    // ---- BN1 stats (apply is fused into fused12's stage); weight prepack ----
    bn_stats_kernel<64><<<1024, 256, 0, stream>>>(x, N_IN, sums1);
    bn_finalize_kernel<64><<<1, 64, 0, stream>>>(sums1, gamma1, beta1, 1.f / N_IN, ss1);
    pack12_kernel<<<512, 256, 0, stream>>>(W1, W2, wf12);
    packS_kernel<<<512, 256, 0, stream>>>(Ws, wfs);

    // ---- fused conv1+conv2 (BN1+ReLU fused into stage) ----
    fused12_kernel<<<nblk, 512, 0, stream>>>(x, wf12, ss1, kstartA, listA, y1, y2b, s2s);
    bn_finalize2_kernel<<<1, 128, 0, stream>>>(s2s, gamma2, beta2, ss2);

    // ---- fused submanifold conv (BN2+ReLU fused into stage, +y2b epilogue) ----
    fusedS_kernel<<<nblk, 512, 0, stream>>>(y1, wfs, ss2, kstartB, listB, y2b, out);
}

// Round 13
// 384.348 us; speedup vs baseline: 1.3315x; 1.0218x over previous
//
#include <hip/hip_runtime.h>

#define K_OFF   8
#define R_PAIRS 62500
#define NPAIRS  500000
#define N_IN    500000
#define N_OUT   125000
#define CIN     64
#define COUT    128
#define BN_EPS  1e-4f
#define NBINS_KC (N_OUT * K_OFF)     // 1,000,000
#define NB2     (2 * NBINS_KC)       // 2,000,000 (both rulebooks)
#define SCAN_E2 8192
#define NSB2    245                  // ceil(2e6 / 8192)
#define BM      32
#define CHUNK   32
#define OLD_TILES 8

typedef __bf16 bf16;
typedef __bf16 bf16x4 __attribute__((ext_vector_type(4)));
typedef __bf16 bf16x8 __attribute__((ext_vector_type(8)));
typedef float  f32x4  __attribute__((ext_vector_type(4)));
typedef unsigned int u32;

// bf16-z byte-offset swizzle: row-stride 1024B, inject row low bits into 16B-slot bits.
__device__ __forceinline__ int zb(int row, int col_bf16) {
    int byte = (row << 10) + (col_bf16 << 1);
    return byte ^ ((row & 7) << 4);
}

// ==================== BN statistics ====================
template<int C>
__global__ void bn_stats_kernel(const float* __restrict__ x, int n_rows,
                                float* __restrict__ sums /* [2C] */) {
    constexpr int CG = C / 4;
    int tid = blockIdx.x * blockDim.x + threadIdx.x;
    int nth = gridDim.x * blockDim.x;
    const float4* x4 = (const float4*)x;
    long n4 = (long)n_rows * CG;
    int cg = tid % CG;
    float s[4] = {0,0,0,0}, q[4] = {0,0,0,0};
    for (long i = tid; i < n4; i += nth) {
        float4 v = x4[i];
        float f[4] = {v.x, v.y, v.z, v.w};
        #pragma unroll
        for (int j = 0; j < 4; j++) { s[j] += f[j]; q[j] += f[j] * f[j]; }
    }
    __shared__ float acc[2 * C];
    for (int i = threadIdx.x; i < 2 * C; i += blockDim.x) acc[i] = 0.f;
    __syncthreads();
    #pragma unroll
    for (int j = 0; j < 4; j++) {
        atomicAdd(&acc[cg * 4 + j], s[j]);
        atomicAdd(&acc[C + cg * 4 + j], q[j]);
    }
    __syncthreads();
    for (int i = threadIdx.x; i < 2 * C; i += blockDim.x) atomicAdd(&sums[i], acc[i]);
}

template<int C>
__global__ void bn_finalize_kernel(const float* __restrict__ sums,
                                   const float* __restrict__ gamma,
                                   const float* __restrict__ beta,
                                   float inv_n, float* __restrict__ ss) {
    int c = threadIdx.x;
    if (c < C) {
        float m  = sums[c] * inv_n;
        float v  = sums[C + c] * inv_n - m * m;
        float sc = gamma[c] * rsqrtf(v + BN_EPS);
        ss[c]     = sc;
        ss[C + c] = beta[c] - m * sc;
    }
}

// BN2 finalize from 64 striped partial-sum copies
__global__ void bn_finalize2_kernel(const float* __restrict__ S /*[64][256]*/,
                                    const float* __restrict__ gamma,
                                    const float* __restrict__ beta,
                                    float* __restrict__ ss) {
    int c = threadIdx.x;   // 128
    float s = 0.f, q = 0.f;
    for (int st = 0; st < 64; st++) { s += S[st * 256 + c]; q += S[st * 256 + 128 + c]; }
    float m = s / (float)N_OUT;
    float v = q / (float)N_OUT - m * m;
    float sc = gamma[c] * rsqrtf(v + BN_EPS);
    ss[c] = sc; ss[128 + c] = beta[c] - m * sc;
}

// ==================== weight prepack (fragment order) ====================
__global__ void pack12_kernel(const float* __restrict__ W1, const float* __restrict__ W2,
                              bf16* __restrict__ Wf) {
    int idx = blockIdx.x * 256 + threadIdx.x;      // 131072
    int j = idx & 7;
    int lane = (idx >> 3) & 63;
    int fi = idx >> 9;            // 0..255
    int ks = fi >> 4, nfrag = fi & 15;
    int k512 = ks * 32 + (lane >> 4) * 8 + j;
    int koff = k512 >> 6, kc = k512 & 63;
    int c = nfrag * 16 + (lane & 15);
    const float* W = (c < 128) ? W1 : W2;
    Wf[idx] = (bf16)W[((long)koff * CIN + kc) * COUT + (c & 127)];
}

__global__ void packS_kernel(const float* __restrict__ Ws, bf16* __restrict__ Wf) {
    int idx = blockIdx.x * 256 + threadIdx.x;      // 131072
    int j = idx & 7;
    int lane = (idx >> 3) & 63;
    int fi = idx >> 9;            // 0..255
    int ksg = fi >> 3, nfrag = fi & 7;
    int k1024 = ksg * 32 + (lane >> 4) * 8 + j;
    int koff = k1024 >> 7, kc = k1024 & 127;
    int c = nfrag * 16 + (lane & 15);
    Wf[idx] = (bf16)Ws[((long)koff * COUT + kc) * COUT + c];
}

// ==================== merged hist over both rulebooks (2M bins) ====================
__global__ void hist2_kernel(const int* __restrict__ o1, const int* __restrict__ os,
                             u32* __restrict__ counts) {
    int p = blockIdx.x * blockDim.x + threadIdx.x;
    int stride = gridDim.x * blockDim.x;
    for (; p < 2 * NPAIRS; p += stride) {
        int bin;
        if (p < NPAIRS) bin = o1[p] * K_OFF + p / R_PAIRS;
        else { int q = p - NPAIRS; bin = NBINS_KC + os[q] * K_OFF + q / R_PAIRS; }
        atomicAdd(&counts[bin], 1u);
    }
}

// ==================== 3-level scan, 8192 elems/block ====================
__global__ void scan1_kernel(const u32* __restrict__ counts, u32* __restrict__ bsum, int n) {
    __shared__ u32 sd[256];
    int tid = threadIdx.x;
    int base = blockIdx.x * SCAN_E2 + tid * 32;
    u32 s = 0;
    #pragma unroll
    for (int j = 0; j < 32; j++) { int i = base + j; if (i < n) s += counts[i]; }
    sd[tid] = s; __syncthreads();
    for (int st = 128; st > 0; st >>= 1) { if (tid < st) sd[tid] += sd[tid + st]; __syncthreads(); }
    if (tid == 0) bsum[blockIdx.x] = sd[0];
}

__global__ void scan2_kernel(u32* __restrict__ bsum, u32* __restrict__ starts, int nb, int n) {
    __shared__ u32 sd[256];
    int tid = threadIdx.x;
    u32 v = (tid < nb) ? bsum[tid] : 0;
    sd[tid] = v; __syncthreads();
    for (int st = 1; st < 256; st <<= 1) {
        u32 t = (tid >= st) ? sd[tid - st] : 0;
        __syncthreads();
        sd[tid] += t;
        __syncthreads();
    }
    if (tid < nb) bsum[tid] = sd[tid] - v;     // exclusive
    if (tid == 255) starts[n] = sd[255];       // total
}

__global__ void scan3_kernel(const u32* __restrict__ counts, const u32* __restrict__ bsum,
                             u32* __restrict__ starts, int n) {
    __shared__ u32 sd[256];
    int tid = threadIdx.x;
    int base = blockIdx.x * SCAN_E2 + tid * 32;
    u32 v[32]; u32 s = 0;
    #pragma unroll
    for (int j = 0; j < 32; j++) { int i = base + j; v[j] = (i < n) ? counts[i] : 0; s += v[j]; }
    sd[tid] = s; __syncthreads();
    for (int st = 1; st < 256; st <<= 1) {
        u32 t = (tid >= st) ? sd[tid - st] : 0;
        __syncthreads();
        sd[tid] += t;
        __syncthreads();
    }
    u32 run = bsum[blockIdx.x] + sd[tid] - s;
    #pragma unroll
    for (int j = 0; j < 32; j++) { int i = base + j; if (i < n) starts[i] = run; run += v[j]; }
}

// ==================== merged build (cursor = counts, atomicSub) ====================
__global__ void buildF2_kernel(const int* __restrict__ i1, const int* __restrict__ o1,
                               const int* __restrict__ is, const int* __restrict__ os,
                               const u32* __restrict__ kstart, u32* __restrict__ counts,
                               u32* __restrict__ listF) {
    int p = blockIdx.x * 256 + threadIdx.x;
    if (p >= 2 * NPAIRS) return;
    int bin, in;
    if (p < NPAIRS) { bin = o1[p] * K_OFF + p / R_PAIRS; in = i1[p]; }
    else { int q = p - NPAIRS; bin = NBINS_KC + os[q] * K_OFF + q / R_PAIRS; in = is[q]; }
    u32 c = atomicSub(&counts[bin], 1u);
    listF[kstart[bin] + c - 1u] = (u32)in;
}

// ==================== fused conv1+conv2: pipelined stage + owner reduce ============
// 512 thr. CHUNK=32: stage = 1 round (16 thr/entry, float4 each), prefetched into pv.
// Owner (row=tid>>4, sl=tid&15): k=sl>>1, ch slice (sl&1)*32. z [32][512] bf16.
__global__ __launch_bounds__(512) void fused12_kernel(
    const float* __restrict__ x, const bf16* __restrict__ Wf, const float* __restrict__ ss1,
    const u32* __restrict__ kstart, const u32* __restrict__ listF,
    bf16* __restrict__ y1, bf16* __restrict__ y2b, float* __restrict__ sums2s)
{
    __shared__ bf16 z[BM * 512];      // 32 KB
    __shared__ bf16 As[CHUNK * 64];   // 4 KB
    __shared__ float s_sc[64], s_sh[64];
    int tid = threadIdx.x, lane = tid & 63, wave = tid >> 6;
    int o0 = blockIdx.x * BM;
    int nrow = min(BM, N_OUT - o0);
    if (tid < 64) { s_sc[tid] = ss1[tid]; s_sh[tid] = ss1[64 + tid]; }

    int row = tid >> 4, sl = tid & 15;
    int ch0 = (sl & 1) * 32;
    u32 sA = 0, eA = 0;
    if (row < nrow) {
        size_t bin = (size_t)(o0 + row) * K_OFF + (sl >> 1);
        sA = kstart[bin]; eA = kstart[bin + 1];
    }
    u32 lo  = kstart[(size_t)o0 * K_OFF];
    u32 hiS = kstart[(size_t)(o0 + nrow) * K_OFF];

    int esl  = tid >> 4;          // staged entry slot 0..31
    int cpos = (tid & 15) * 4;    // float offset within 64-float row
    float4 pv;

    auto issue = [&](u32 base) {
        u32 idx = base + esl;
        u32 in = (idx < hiS) ? listF[idx] : 0u;
        pv = *(const float4*)(x + (size_t)in * 64 + cpos);
    };

    f32x4 a[8];
    #pragma unroll
    for (int g = 0; g < 8; g++) a[g] = (f32x4)(0.f);

    if (lo < hiS) issue(lo);
    for (u32 cb = lo; cb < hiS; cb += CHUNK) {
        int nE = (int)min((u32)CHUNK, hiS - cb);
        __syncthreads();              // As free; s_sc ready on first iter
        if (esl < nE) {
            float f[4] = {pv.x, pv.y, pv.z, pv.w};
            bf16x4 h;
            #pragma unroll
            for (int j = 0; j < 4; j++)
                h[j] = (bf16)fmaxf(f[j] * s_sc[cpos + j] + s_sh[cpos + j], 0.f);
            *(bf16x4*)((char*)As + ((esl * 128 + cpos * 2) ^ ((esl & 7) << 4))) = h;
        }
        __syncthreads();              // As ready
        if (cb + CHUNK < hiS) issue(cb + CHUNK);   // overlap next loads with reduce
        u32 pa = max(sA, cb), pb = min(eA, cb + (u32)CHUNK);
        for (u32 p = pa; p < pb; p++) {
            int slot = (int)(p - cb);
            #pragma unroll
            for (int u = 0; u < 4; u++) {
                int bo = (slot * 128 + ch0 * 2 + u * 16) ^ ((slot & 7) << 4);
                int4 vi = *(const int4*)((const char*)As + bo);
                bf16x8 hv = *(bf16x8*)&vi;
                #pragma unroll
                for (int j = 0; j < 8; j++)
                    a[u * 2 + (j >> 2)][j & 3] += (float)hv[j];
            }
        }
    }
    __syncthreads();

    // z write (full coverage: 32 rows x 16 slices)
    {
        int colb = sl * 32;   // == (sl>>1)*64 + (sl&1)*32
        #pragma unroll
        for (int u = 0; u < 4; u++) {
            bf16x8 h;
            #pragma unroll
            for (int j = 0; j < 8; j++) h[j] = (bf16)a[u * 2 + (j >> 2)][j & 3];
            *(bf16x8*)((char*)z + zb(row, colb + u * 8)) = h;
        }
    }
    __syncthreads();

    // ---- GEMM [32 x 512] x [512 x 256], 8 waves: wave -> cat cols wave*32..+32 ----
    int l15 = lane & 15, kr0 = (lane >> 4) * 8;
    f32x4 acc[2][2];
    #pragma unroll
    for (int m = 0; m < 2; m++)
        #pragma unroll
        for (int nf = 0; nf < 2; nf++) acc[m][nf] = (f32x4)(0.f);

    for (int ks = 0; ks < 16; ks++) {
        int colb = ks * 32 + kr0;
        bf16x8 af0 = *(bf16x8*)((char*)z + zb(l15, colb));
        bf16x8 af1 = *(bf16x8*)((char*)z + zb(l15 + 16, colb));
        #pragma unroll
        for (int nf = 0; nf < 2; nf++) {
            bf16x8 bf = *(const bf16x8*)(Wf + ((size_t)(ks * 16 + wave * 2 + nf) * 64 + lane) * 8);
            acc[0][nf] = __builtin_amdgcn_mfma_f32_16x16x32_bf16(af0, bf, acc[0][nf], 0, 0, 0);
            acc[1][nf] = __builtin_amdgcn_mfma_f32_16x16x32_bf16(af1, bf, acc[1][nf], 0, 0, 0);
        }
    }
    __syncthreads();   // z reads done -> reuse as stage

    // stage bf16 [32 rows][256 cat cols] (16 KB)
    bf16* st = z;
    int rb = (lane >> 4) * 4;
    #pragma unroll
    for (int m = 0; m < 2; m++)
        #pragma unroll
        for (int nf = 0; nf < 2; nf++)
            #pragma unroll
            for (int j = 0; j < 4; j++)
                st[(m * 16 + rb + j) * 256 + wave * 32 + nf * 16 + l15] = (bf16)acc[m][nf][j];
    __syncthreads();

    // BN2 stats over y1 cols (0..127), striped atomics
    if (tid < 128) {
        float s = 0.f, q = 0.f;
        for (int r = 0; r < nrow; r++) { float v = (float)st[r * 256 + tid]; s += v; q += v * v; }
        int sb = (blockIdx.x & 63) * 256;
        atomicAdd(&sums2s[sb + tid], s);
        atomicAdd(&sums2s[sb + 128 + tid], q);
    }
    // output: 512 threads = 32 rows x 16 segs
    {
        int orow = tid >> 4, seg = tid & 15;
        if (orow < nrow) {
            const int4* src = (const int4*)(st + orow * 256 + seg * 16);
            int4 v0 = src[0], v1 = src[1];
            bf16* dst = (seg < 8) ? (y1  + (size_t)(o0 + orow) * 128 + seg * 16)
                                  : (y2b + (size_t)(o0 + orow) * 128 + (seg - 8) * 16);
            ((int4*)dst)[0] = v0; ((int4*)dst)[1] = v1;
        }
    }
}

// ==================== fused submanifold conv: pipelined stage + owner reduce =======
// 512 thr. CHUNK=32 (16 thr/entry, int4=8 bf16 each). Owner (row, sl): ch slice
// (sl&3)*32, bins k=sl>>2 (aA) and 4+(sl>>2) (aB), both reduced per chunk.
__global__ __launch_bounds__(512) void fusedS_kernel(
    const bf16* __restrict__ y1, const bf16* __restrict__ Wf, const float* __restrict__ ss2,
    const u32* __restrict__ kstart, const u32* __restrict__ listF,
    const bf16* __restrict__ y2b, float* __restrict__ out)
{
    __shared__ bf16 z[BM * 512];       // 32 KB
    __shared__ bf16 As[CHUNK * 128];   // 8 KB
    __shared__ float s_sc[128], s_sh[128];
    int tid = threadIdx.x, lane = tid & 63, wave = tid >> 6;
    int o0 = blockIdx.x * BM;
    int nrow = min(BM, N_OUT - o0);
    if (tid < 128) { s_sc[tid] = ss2[tid]; s_sh[tid] = ss2[128 + tid]; }

    int row = tid >> 4, sl = tid & 15;
    int kq = sl >> 2, ch0 = (sl & 3) * 32;
    u32 sA = 0, eA = 0, sB = 0, eB = 0;
    if (row < nrow) {
        size_t binb = (size_t)(o0 + row) * K_OFF;
        sA = kstart[binb + kq];     eA = kstart[binb + kq + 1];
        sB = kstart[binb + 4 + kq]; eB = kstart[binb + 4 + kq + 1];
    }
    u32 lo  = kstart[(size_t)o0 * K_OFF];
    u32 hiS = kstart[(size_t)(o0 + nrow) * K_OFF];

    int esl  = tid >> 4;          // staged entry slot 0..31
    int cpos = (tid & 15) * 8;    // bf16 offset within 128-ch row
    int4 pv;

    auto issue = [&](u32 base) {
        u32 idx = base + esl;
        u32 in = (idx < hiS) ? listF[idx] : 0u;
        pv = *(const int4*)(y1 + (size_t)in * 128 + cpos);
    };

    f32x4 aA[8], aB[8];
    #pragma unroll
    for (int g = 0; g < 8; g++) { aA[g] = (f32x4)(0.f); aB[g] = (f32x4)(0.f); }

    if (lo < hiS) issue(lo);
    for (u32 cb = lo; cb < hiS; cb += CHUNK) {
        int nE = (int)min((u32)CHUNK, hiS - cb);
        __syncthreads();              // As free; s_sc ready on first iter
        if (esl < nE) {
            bf16x8 hv = *(bf16x8*)&pv;
            bf16x8 ho;
            #pragma unroll
            for (int j = 0; j < 8; j++)
                ho[j] = (bf16)fmaxf((float)hv[j] * s_sc[cpos + j] + s_sh[cpos + j], 0.f);
            *(bf16x8*)((char*)As + ((esl * 256 + cpos * 2) ^ ((esl & 7) << 4))) = ho;
        }
        __syncthreads();              // As ready
        if (cb + CHUNK < hiS) issue(cb + CHUNK);
        u32 pa = max(sA, cb), pb = min(eA, cb + (u32)CHUNK);
        for (u32 p = pa; p < pb; p++) {
            int slot = (int)(p - cb);
            #pragma unroll
            for (int u = 0; u < 4; u++) {
                int bo = (slot * 256 + ch0 * 2 + u * 16) ^ ((slot & 7) << 4);
                int4 vi = *(const int4*)((const char*)As + bo);
                bf16x8 hv = *(bf16x8*)&vi;
                #pragma unroll
                for (int j = 0; j < 8; j++)
                    aA[u * 2 + (j >> 2)][j & 3] += (float)hv[j];
            }
        }
        pa = max(sB, cb); pb = min(eB, cb + (u32)CHUNK);
        for (u32 p = pa; p < pb; p++) {
            int slot = (int)(p - cb);
            #pragma unroll
            for (int u = 0; u < 4; u++) {
                int bo = (slot * 256 + ch0 * 2 + u * 16) ^ ((slot & 7) << 4);
                int4 vi = *(const int4*)((const char*)As + bo);
                bf16x8 hv = *(bf16x8*)&vi;
                #pragma unroll
                for (int j = 0; j < 8; j++)
                    aB[u * 2 + (j >> 2)][j & 3] += (float)hv[j];
            }
        }
    }

    int l15 = lane & 15, kr0 = (lane >> 4) * 8;
    f32x4 acc[2];
    acc[0] = (f32x4)(0.f); acc[1] = (f32x4)(0.f);
    int colb0 = sl * 32;   // == kq*128 + ch0

    #pragma unroll
    for (int h = 0; h < 2; h++) {
        __syncthreads();   // h=0: reduce done; h=1: GEMM h=0 z reads done
        {
            #pragma unroll
            for (int u = 0; u < 4; u++) {
                bf16x8 hv;
                #pragma unroll
                for (int j = 0; j < 8; j++)
                    hv[j] = (bf16)((h == 0 ? aA : aB)[u * 2 + (j >> 2)][j & 3]);
                *(bf16x8*)((char*)z + zb(row, colb0 + u * 8)) = hv;
            }
        }
        __syncthreads();

        for (int ks = 0; ks < 16; ks++) {
            int colb = ks * 32 + kr0;
            bf16x8 af0 = *(bf16x8*)((char*)z + zb(l15, colb));
            bf16x8 af1 = *(bf16x8*)((char*)z + zb(l15 + 16, colb));
            int fi = (h * 16 + ks) * 8 + wave;
            bf16x8 bf = *(const bf16x8*)(Wf + ((size_t)fi * 64 + lane) * 8);
            acc[0] = __builtin_amdgcn_mfma_f32_16x16x32_bf16(af0, bf, acc[0], 0, 0, 0);
            acc[1] = __builtin_amdgcn_mfma_f32_16x16x32_bf16(af1, bf, acc[1], 0, 0, 0);
        }
    }
    __syncthreads();

    // stage fp32 [32][128] (16 KB, inside z)
    float* zf = (float*)z;
    int rb = (lane >> 4) * 4;
    #pragma unroll
    for (int m = 0; m < 2; m++)
        #pragma unroll
        for (int j = 0; j < 4; j++)
            zf[(m * 16 + rb + j) * 128 + wave * 16 + l15] = acc[m][j];
    __syncthreads();

    {
        int orow = tid >> 4, seg = tid & 15;   // 8 floats each
        if (orow < nrow) {
            f32x4 s0 = *(f32x4*)&zf[orow * 128 + seg * 8];
            f32x4 s1 = *(f32x4*)&zf[orow * 128 + seg * 8 + 4];
            int4 yv = *(const int4*)(y2b + (size_t)(o0 + orow) * 128 + seg * 8);
            bf16x8 hy = *(bf16x8*)&yv;
            float4 w0 = make_float4(s0[0] + (float)hy[0], s0[1] + (float)hy[1],
                                    s0[2] + (float)hy[2], s0[3] + (float)hy[3]);
            float4 w1 = make_float4(s1[0] + (float)hy[4], s1[1] + (float)hy[5],
                                    s1[2] + (float)hy[6], s1[3] + (float)hy[7]);
            float* dst = out + (size_t)(o0 + orow) * 128 + seg * 8;
            *(float4*)dst = w0;
            *(float4*)(dst + 4) = w1;
        }
    }
}

// ==================== fallback (round-1 atomic path) ====================
__global__ __launch_bounds__(256) void conv12_atomic_kernel(
    const float* __restrict__ x,
    const float* __restrict__ W1, const float* __restrict__ W2,
    const int* __restrict__ in_idx, const int* __restrict__ out_idx,
    const float* __restrict__ ss1,
    float* __restrict__ y1, float* __restrict__ y2)
{
    int k    = blockIdx.y;
    int tid  = threadIdx.x;
    int wave = tid >> 6, lane = tid & 63;

    __shared__ bf16 As[64 * 64];
    __shared__ int  s_out[64];
    __shared__ float s_sc[64], s_sh[64];
    char* asb = (char*)As;

    if (tid < 64) { s_sc[tid] = ss1[tid]; s_sh[tid] = ss1[64 + tid]; }

    const float* Wk = ((wave & 2) ? W2 : W1) + (long)k * CIN * COUT;
    int nbase = (wave & 1) * 64;
    int l15 = lane & 15;
    int kr0 = (lane >> 4) * 8;

    bf16x8 bfrag[2][4];
    #pragma unroll
    for (int ks = 0; ks < 2; ks++)
        #pragma unroll
        for (int nf = 0; nf < 4; nf++) {
            const float* p = Wk + (long)(ks * 32 + kr0) * COUT + nbase + nf * 16 + l15;
            bf16x8 b;
            #pragma unroll
            for (int j = 0; j < 8; j++) b[j] = (bf16)p[(long)j * COUT];
            bfrag[ks][nf] = b;
        }

    const int* in_k  = in_idx  + k * R_PAIRS;
    const int* out_k = out_idx + k * R_PAIRS;
    float* ybase = (wave & 2) ? y2 : y1;

    int grow = tid >> 2;
    int gcol = (tid & 3) * 16;

    __syncthreads();

    for (int t = 0; t < OLD_TILES; t++) {
        int pair0 = blockIdx.x * (OLD_TILES * 64) + t * 64;
        {
            int p = pair0 + grow;
            bool valid = p < R_PAIRS;
            long src = valid ? (long)in_k[p] : 0;
            const float4* xr = (const float4*)(x + src * CIN + gcol);
            #pragma unroll
            for (int g = 0; g < 2; g++) {
                float4 va = make_float4(0, 0, 0, 0), vb = va;
                if (valid) { va = xr[g * 2]; vb = xr[g * 2 + 1]; }
                float f[8] = {va.x, va.y, va.z, va.w, vb.x, vb.y, vb.z, vb.w};
                bf16x8 h;
                #pragma unroll
                for (int j = 0; j < 8; j++) {
                    int c = gcol + g * 8 + j;
                    h[j] = (bf16)fmaxf(f[j] * s_sc[c] + s_sh[c], 0.f);
                }
                int boff = ((grow * 128) + (gcol + g * 8) * 2) ^ ((grow & 7) << 4);
                *(bf16x8*)(asb + boff) = h;
            }
        }
        if (tid < 64) {
            int p = pair0 + tid;
            s_out[tid] = (p < R_PAIRS) ? out_k[p] : -1;
        }
        __syncthreads();

        f32x4 acc[4][4];
        #pragma unroll
        for (int m = 0; m < 4; m++)
            #pragma unroll
            for (int n = 0; n < 4; n++) acc[m][n] = (f32x4)(0.f);

        #pragma unroll
        for (int ks = 0; ks < 2; ks++) {
            bf16x8 af[4];
            #pragma unroll
            for (int m = 0; m < 4; m++) {
                int rrow = m * 16 + l15;
                int boff = (rrow * 128 + (ks * 32 + kr0) * 2) ^ ((rrow & 7) << 4);
                af[m] = *(bf16x8*)(asb + boff);
            }
            #pragma unroll
            for (int m = 0; m < 4; m++)
                #pragma unroll
                for (int nf = 0; nf < 4; nf++)
                    acc[m][nf] = __builtin_amdgcn_mfma_f32_16x16x32_bf16(
                        af[m], bfrag[ks][nf], acc[m][nf], 0, 0, 0);
        }

        int rbase = (lane >> 4) * 4;
        #pragma unroll
        for (int m = 0; m < 4; m++)
            #pragma unroll
            for (int j = 0; j < 4; j++) {
                int o = s_out[m * 16 + rbase + j];
                if (o >= 0)
                    #pragma unroll
                    for (int nf = 0; nf < 4; nf++)
                        atomicAdd(&ybase[(long)o * COUT + nbase + nf * 16 + l15],
                                  acc[m][nf][j]);
            }
        __syncthreads();
    }
}

__global__ __launch_bounds__(256) void convs_atomic_kernel(
    const float* __restrict__ y1,
    const float* __restrict__ Ws,
    const int* __restrict__ in_idx, const int* __restrict__ out_idx,
    const float* __restrict__ ss2,
    float* __restrict__ out)
{
    int k    = blockIdx.y;
    int tid  = threadIdx.x;
    int wave = tid >> 6, lane = tid & 63;

    __shared__ bf16 As[64 * 128];
    __shared__ int  s_out[64];
    __shared__ float s_sc[128], s_sh[128];
    char* asb = (char*)As;

    if (tid < 128) { s_sc[tid] = ss2[tid]; s_sh[tid] = ss2[128 + tid]; }

    const float* Wk = Ws + (long)k * COUT * COUT;
    int nbase = wave * 32;
    int l15 = lane & 15;
    int kr0 = (lane >> 4) * 8;

    bf16x8 bfrag[4][2];
    #pragma unroll
    for (int ks = 0; ks < 4; ks++)
        #pragma unroll
        for (int nf = 0; nf < 2; nf++) {
            const float* p = Wk + (long)(ks * 32 + kr0) * COUT + nbase + nf * 16 + l15;
            bf16x8 b;
            #pragma unroll
            for (int j = 0; j < 8; j++) b[j] = (bf16)p[(long)j * COUT];
            bfrag[ks][nf] = b;
        }

    const int* in_k  = in_idx  + k * R_PAIRS;
    const int* out_k = out_idx + k * R_PAIRS;

    int grow = tid >> 2;
    int gcol = (tid & 3) * 32;

    __syncthreads();

    for (int t = 0; t < OLD_TILES; t++) {
        int pair0 = blockIdx.x * (OLD_TILES * 64) + t * 64;
        {
            int p = pair0 + grow;
            bool valid = p < R_PAIRS;
            long src = valid ? (long)in_k[p] : 0;
            const float4* yr = (const float4*)(y1 + src * COUT + gcol);
            #pragma unroll
            for (int g = 0; g < 4; g++) {
                float4 va = make_float4(0, 0, 0, 0), vb = va;
                if (valid) { va = yr[g * 2]; vb = yr[g * 2 + 1]; }
                float f[8] = {va.x, va.y, va.z, va.w, vb.x, vb.y, vb.z, vb.w};
                bf16x8 h;
                #pragma unroll
                for (int j = 0; j < 8; j++) {
                    int c = gcol + g * 8 + j;
                    h[j] = (bf16)fmaxf(f[j] * s_sc[c] + s_sh[c], 0.f);
                }
                int boff = (grow * 256 + (gcol + g * 8) * 2) ^ ((grow & 7) << 4);
                *(bf16x8*)(asb + boff) = h;
            }
        }
        if (tid < 64) {
            int p = pair0 + tid;
            s_out[tid] = (p < R_PAIRS) ? out_k[p] : -1;
        }
        __syncthreads();

        f32x4 acc[4][2];
        #pragma unroll
        for (int m = 0; m < 4; m++)
            #pragma unroll
            for (int n = 0; n < 2; n++) acc[m][n] = (f32x4)(0.f);

        #pragma unroll
        for (int ks = 0; ks < 4; ks++) {
            bf16x8 af[4];
            #pragma unroll
            for (int m = 0; m < 4; m++) {
                int rrow = m * 16 + l15;
                int boff = (rrow * 256 + (ks * 32 + kr0) * 2) ^ ((rrow & 7) << 4);
                af[m] = *(bf16x8*)(asb + boff);
            }
            #pragma unroll
            for (int m = 0; m < 4; m++)
                #pragma unroll
                for (int nf = 0; nf < 2; nf++)
                    acc[m][nf] = __builtin_amdgcn_mfma_f32_16x16x32_bf16(
                        af[m], bfrag[ks][nf], acc[m][nf], 0, 0, 0);
        }

        int rbase = (lane >> 4) * 4;
        #pragma unroll
        for (int m = 0; m < 4; m++)
            #pragma unroll
            for (int j = 0; j < 4; j++) {
                int o = s_out[m * 16 + rbase + j];
                if (o >= 0)
                    #pragma unroll
                    for (int nf = 0; nf < 2; nf++)
                        atomicAdd(&out[(long)o * COUT + nbase + nf * 16 + l15],
                                  acc[m][nf][j]);
            }
        __syncthreads();
    }
}

// ==================== host ====================
extern "C" void kernel_launch(void* const* d_in, const int* in_sizes, int n_in,
                              void* d_out, int out_size, void* d_ws, size_t ws_size,
                              hipStream_t stream) {
    const float* x       = (const float*)d_in[0];
    const float* gamma1  = (const float*)d_in[1];
    const float* beta1   = (const float*)d_in[2];
    const float* gamma2  = (const float*)d_in[3];
    const float* beta2   = (const float*)d_in[4];
    const float* W1      = (const float*)d_in[5];
    const float* Ws      = (const float*)d_in[6];
    const float* W2      = (const float*)d_in[7];
    const int*   in_idx1   = (const int*)d_in[8];
    const int*   out_idx1  = (const int*)d_in[9];
    const int*   in_idx_s  = (const int*)d_in[10];
    const int*   out_idx_s = (const int*)d_in[11];

    float* out = (float*)d_out;
    char*  ws  = (char*)d_ws;

    auto a256 = [](size_t v) { return (v + 255) & ~(size_t)255; };

    size_t off_y1      = 0;                                    // bf16 y1: 32 MB
    size_t off_y2b     = a256(off_y1 + 32000000);              // bf16 y2b: 32 MB
    size_t off_stats   = a256(off_y2b + 32000000);             // 4 KB (sums1,ss1,ss2)
    size_t off_s2s     = a256(off_stats + 4096);               // 64 KB
    size_t off_counts  = a256(off_s2s + 65536);                // 8 MB (2M bins)
    size_t off_kstart  = a256(off_counts + 4ull * NB2);        // 8 MB + 4
    size_t off_bsum    = a256(off_kstart + 4ull * (NB2 + 1));  // 1 KB
    size_t off_list    = a256(off_bsum + 1024);                // 4 MB (1M entries)
    size_t off_wf12    = a256(off_list + 4ull * 2 * NPAIRS);   // 256 KB
    size_t off_wfs     = a256(off_wf12 + 262144);              // 256 KB
    size_t need        = off_wfs + 262144;

    if (need > ws_size) {
        // -------- fallback: atomic path (needs only 64 MB + 4 KB) --------
        float* y1f   = (float*)ws;
        float* stats = y1f + (long)N_OUT * COUT;
        float* sums1 = stats;
        float* ss1   = stats + 128;
        float* sums2 = stats + 256;
        float* ss2   = stats + 512;

        hipMemsetAsync(d_out, 0, (size_t)N_OUT * COUT * 4, stream);
        hipMemsetAsync(d_ws,  0, (size_t)N_OUT * COUT * 4 + 768 * 4, stream);

        bn_stats_kernel<64><<<1024, 256, 0, stream>>>(x, N_IN, sums1);
        bn_finalize_kernel<64><<<1, 64, 0, stream>>>(sums1, gamma1, beta1, 1.f / N_IN, ss1);

        dim3 cgrid((R_PAIRS + OLD_TILES * 64 - 1) / (OLD_TILES * 64), K_OFF);
        conv12_atomic_kernel<<<cgrid, 256, 0, stream>>>(x, W1, W2, in_idx1, out_idx1, ss1, y1f, out);

        bn_stats_kernel<128><<<1024, 256, 0, stream>>>(y1f, N_OUT, sums2);
        bn_finalize_kernel<128><<<1, 128, 0, stream>>>(sums2, gamma2, beta2, 1.f / N_OUT, ss2);

        convs_atomic_kernel<<<cgrid, 256, 0, stream>>>(y1f, Ws, in_idx_s, out_idx_s, ss2, out);
        return;
    }

    bf16*  y1      = (bf16*)(ws + off_y1);
    bf16*  y2b     = (bf16*)(ws + off_y2b);
    float* sums1   = (float*)(ws + off_stats);    // [256]
    float* ss1     = sums1 + 256;                 // [256]
    float* ss2     = sums1 + 512;                 // [256]
    float* s2s     = (float*)(ws + off_s2s);      // [64][256]
    u32*   counts  = (u32*)(ws + off_counts);
    u32*   kstart  = (u32*)(ws + off_kstart);
    u32*   bsum    = (u32*)(ws + off_bsum);
    u32*   list    = (u32*)(ws + off_list);
    bf16*  wf12    = (bf16*)(ws + off_wf12);
    bf16*  wfs     = (bf16*)(ws + off_wfs);

    int nblk = (N_OUT + BM - 1) / BM;    // 3907

    // ---- init ----
    hipMemsetAsync(ws + off_stats, 0, off_counts - off_stats, stream);   // stats + s2s
    hipMemsetAsync(counts, 0, 4ull * NB2, stream);

    // ---- merged rulebook sort (both in one 2M-bin pipeline) ----
    hist2_kernel<<<1024, 256, 0, stream>>>(out_idx1, out_idx_s, counts);
    scan1_kernel<<<NSB2, 256, 0, stream>>>(counts, bsum, NB2);
    scan2_kernel<<<1, 256, 0, stream>>>(bsum, kstart, NSB2, NB2);
    scan3_kernel<<<NSB2, 256, 0, stream>>>(counts, bsum, kstart, NB2);
    buildF2_kernel<<<(2 * NPAIRS + 255) / 256, 256, 0, stream>>>(
        in_idx1, out_idx1, in_idx_s, out_idx_s, kstart, counts, list);

    // ---- BN1 stats (apply fused into fused12's stage); weight prepack ----
    bn_stats_kernel<64><<<1024, 256, 0, stream>>>(x, N_IN, sums1);
    bn_finalize_kernel<64><<<1, 64, 0, stream>>>(sums1, gamma1, beta1, 1.f / N_IN, ss1);
    pack12_kernel<<<512, 256, 0, stream>>>(W1, W2, wf12);
    packS_kernel<<<512, 256, 0, stream>>>(Ws, wfs);

    // ---- fused conv1+conv2 (BN1+ReLU fused into stage) ----
    fused12_kernel<<<nblk, 512, 0, stream>>>(x, wf12, ss1, kstart, list, y1, y2b, s2s);
    bn_finalize2_kernel<<<1, 128, 0, stream>>>(s2s, gamma2, beta2, ss2);

    // ---- fused submanifold conv (BN2+ReLU fused into stage, +y2b epilogue) ----
    fusedS_kernel<<<nblk, 512, 0, stream>>>(y1, wfs, ss2, kstart + NBINS_KC, list, y2b, out);
}